// Round 1
// baseline (1577.115 us; speedup 1.0000x reference)
//
#include <hip/hip_runtime.h>
#include <hip/hip_bf16.h>

#define B_ 4
#define T_ 512
#define N_ 16
#define D_ 256
#define H_ 8
#define DK_ 32
#define NT_ (N_ * T_)
#define CTS_ 6
#define CN_ 4
#define CE_ 3
#define TSE_ 192
#define AUXE_ 64

typedef unsigned long long ull;

// ---------------------------------------------------------------- PE table
__global__ __launch_bounds__(256) void pe_kernel(float* pe) {
    int t = blockIdx.x;
    int d = threadIdx.x;
    int j = d >> 1;
    float div = expf((float)(2 * j) * (-9.210340371976184f / 256.0f)); // -ln(10000)/D
    float a = (float)t * div;
    pe[t * D_ + d] = (d & 1) ? cosf(a) : sinf(a);
}

// ---------------------------------------------------------- mask -> bitmask
__global__ __launch_bounds__(256) void maskbits_kernel(const int* __restrict__ mask,
                                                       ull* __restrict__ bits) {
    int row = blockIdx.x;  // b*T + t
    const int* mrow = mask + (size_t)row * NT_;
    int lane = threadIdx.x & 63, wave = threadIdx.x >> 6;
    for (int it = 0; it < NT_ / 256; ++it) {
        int k = it * 256 + wave * 64 + lane;
        ull bal = __ballot(mrow[k] != 0);
        if (lane == 0) bits[(size_t)row * (NT_ / 64) + (k >> 6)] = bal;
    }
}

// -------------------------------------------------- KV build + K/V projection
__global__ __launch_bounds__(256) void kv_kernel(
    const float* __restrict__ md, const float* __restrict__ na, const float* __restrict__ ea,
    const float* __restrict__ W_ts1, const float* __restrict__ b_ts1,
    const float* __restrict__ W_ts2, const float* __restrict__ b_ts2,
    const float* __restrict__ W_a1, const float* __restrict__ b_a1,
    const float* __restrict__ W_a2, const float* __restrict__ b_a2,
    const float* __restrict__ W_e1, const float* __restrict__ b_e1,
    const float* __restrict__ W_e2, const float* __restrict__ b_e2,
    const float* __restrict__ Wk, const float* __restrict__ bk,
    const float* __restrict__ Wv, const float* __restrict__ bv,
    const float* __restrict__ pe, float* __restrict__ Kp, float* __restrict__ Vp) {
    int blk = blockIdx.x;
    int t0 = (blk & 31) * 16;
    int n = (blk >> 5) & 15;
    int b = blk >> 9;
    int tid = threadIdx.x;

    __shared__ float s_in[CTS_ + CN_ + CE_][16];
    __shared__ float s_hts[16][TSE_];
    __shared__ float s_haux[16][AUXE_];
    __shared__ float s_hedge[16][D_];
    __shared__ float s_key[16][D_];
    __shared__ float s_val[16][D_];

    if (tid < (CTS_ + CN_ + CE_) * 16) {
        int c = tid >> 4, r = tid & 15;
        int t = t0 + r;
        float v;
        if (c < CTS_)
            v = md[(((size_t)b * N_ + n) * CTS_ + c) * T_ + t];
        else if (c < CTS_ + CN_)
            v = na[(((size_t)b * N_ + n) * CN_ + (c - CTS_)) * T_ + t];
        else
            v = ea[(((size_t)b * N_ + n) * CE_ + (c - CTS_ - CN_)) * T_ + t];
        s_in[c][r] = v;
    }
    __syncthreads();

    if (tid < TSE_) {
        for (int r = 0; r < 16; ++r) {
            float acc = b_ts1[tid];
#pragma unroll
            for (int c = 0; c < CTS_; ++c) acc += s_in[c][r] * W_ts1[c * TSE_ + tid];
            s_hts[r][tid] = fmaxf(acc, 0.f);
        }
    }
    if (tid < AUXE_) {
        for (int r = 0; r < 16; ++r) {
            float acc = b_a1[tid];
#pragma unroll
            for (int c = 0; c < CN_; ++c) acc += s_in[CTS_ + c][r] * W_a1[c * AUXE_ + tid];
            s_haux[r][tid] = fmaxf(acc, 0.f);
        }
    }
    {
        for (int r = 0; r < 16; ++r) {
            float acc = b_e1[tid];
#pragma unroll
            for (int c = 0; c < CE_; ++c) acc += s_in[CTS_ + CN_ + c][r] * W_e1[c * D_ + tid];
            s_hedge[r][tid] = fmaxf(acc, 0.f);
        }
    }
    __syncthreads();

    float nbr[16], edg[16];
    if (tid < TSE_) {
#pragma unroll
        for (int r = 0; r < 16; ++r) nbr[r] = b_ts2[tid];
        for (int e = 0; e < TSE_; ++e) {
            float w = W_ts2[e * TSE_ + tid];
#pragma unroll
            for (int r = 0; r < 16; ++r) nbr[r] += s_hts[r][e] * w;
        }
    } else {
        int d2 = tid - TSE_;
#pragma unroll
        for (int r = 0; r < 16; ++r) nbr[r] = b_a2[d2];
        for (int e = 0; e < AUXE_; ++e) {
            float w = W_a2[e * AUXE_ + d2];
#pragma unroll
            for (int r = 0; r < 16; ++r) nbr[r] += s_haux[r][e] * w;
        }
    }
    {
#pragma unroll
        for (int r = 0; r < 16; ++r) edg[r] = b_e2[tid];
        for (int e = 0; e < D_; ++e) {
            float w = W_e2[e * D_ + tid];
#pragma unroll
            for (int r = 0; r < 16; ++r) edg[r] += s_hedge[r][e] * w;
        }
    }
    for (int r = 0; r < 16; ++r) {
        int t = t0 + r;
        float p = pe[t * D_ + tid];
        s_key[r][tid] = nbr[r] * edg[r] + p;
        s_val[r][tid] = nbr[r] + p;
    }
    __syncthreads();

    float kacc[16], vacc[16];
#pragma unroll
    for (int r = 0; r < 16; ++r) {
        kacc[r] = bk[tid];
        vacc[r] = bv[tid];
    }
    for (int e = 0; e < D_; ++e) {
        float wk = Wk[e * D_ + tid];
        float wv = Wv[e * D_ + tid];
#pragma unroll
        for (int r = 0; r < 16; ++r) {
            kacc[r] += s_key[r][e] * wk;
            vacc[r] += s_val[r][e] * wv;
        }
    }
    size_t base = ((size_t)b * NT_ + (size_t)n * T_ + t0) * D_;
    for (int r = 0; r < 16; ++r) {
        Kp[base + (size_t)r * D_ + tid] = kacc[r];
        Vp[base + (size_t)r * D_ + tid] = vacc[r];
    }
}

// -------------------------------------------- xq = x + pe, LayerNorm, Q proj
__global__ __launch_bounds__(256) void q_kernel(
    const float* __restrict__ x, const float* __restrict__ pe,
    const float* __restrict__ Wq, const float* __restrict__ bq,
    const float* __restrict__ ln_g, const float* __restrict__ ln_b,
    float* __restrict__ xq, float* __restrict__ Qp) {
    int blk = blockIdx.x;
    int t0 = (blk & 31) * 16;
    int b = blk >> 5;
    int tid = threadIdx.x;

    __shared__ float s_xn[16][D_];
    __shared__ float s_red[8];

    for (int r = 0; r < 16; ++r) {
        int t = t0 + r;
        size_t off = ((size_t)b * T_ + t) * D_ + tid;
        float v = x[off] + pe[t * D_ + tid];
        xq[off] = v;
        float s1 = v, s2 = v * v;
#pragma unroll
        for (int o = 32; o; o >>= 1) {
            s1 += __shfl_down(s1, o, 64);
            s2 += __shfl_down(s2, o, 64);
        }
        if ((tid & 63) == 0) {
            s_red[tid >> 6] = s1;
            s_red[4 + (tid >> 6)] = s2;
        }
        __syncthreads();
        float t1 = s_red[0] + s_red[1] + s_red[2] + s_red[3];
        float t2 = s_red[4] + s_red[5] + s_red[6] + s_red[7];
        float mu = t1 * (1.f / D_);
        float var = t2 * (1.f / D_) - mu * mu;
        float rs = rsqrtf(var + 1e-6f);
        s_xn[r][tid] = (v - mu) * rs * ln_g[tid] + ln_b[tid];
        __syncthreads();
    }

    float acc[16];
#pragma unroll
    for (int r = 0; r < 16; ++r) acc[r] = bq[tid];
    for (int e = 0; e < D_; ++e) {
        float w = Wq[e * D_ + tid];
#pragma unroll
        for (int r = 0; r < 16; ++r) acc[r] += s_xn[r][e] * w;
    }
    for (int r = 0; r < 16; ++r) {
        Qp[((size_t)b * T_ + t0 + r) * D_ + tid] = acc[r];
    }
}

// ------------------------------------------------ flash attention, f32
__global__ __launch_bounds__(256) void attn_kernel(
    const float* __restrict__ Qp, const float* __restrict__ Kp, const float* __restrict__ Vp,
    const ull* __restrict__ bits, float* __restrict__ ctx_out) {
    int blk = blockIdx.x;
    int qt = blk & 15;
    int h = (blk >> 4) & 7;
    int b = blk >> 7;
    int tid = threadIdx.x, lane = tid & 63, wave = tid >> 6;

    __shared__ float s_q[32][33];
    __shared__ float s_k[64][33];
    __shared__ float s_v[64][33];
    __shared__ float s_p[32][65];
    __shared__ float s_m[32], s_l[32], s_scale[32];

    {
        int qi = tid >> 3, d0 = (tid & 7) * 4;
        const float* qrow = Qp + ((size_t)b * T_ + qt * 32 + qi) * D_ + h * DK_;
#pragma unroll
        for (int j = 0; j < 4; ++j) s_q[qi][d0 + j] = qrow[d0 + j];
        if (tid < 32) {
            s_m[tid] = -1e30f;
            s_l[tid] = 0.f;
        }
    }
    float cacc[4] = {0.f, 0.f, 0.f, 0.f};
    int qi_pv = tid >> 3, d0_pv = (tid & 7) * 4;
    int qi0 = wave * 8;
    const float scale = 0.1767766952966369f;  // 1/sqrt(32)

    for (int kt = 0; kt < NT_ / 64; ++kt) {
        __syncthreads();
        {
            int r = tid >> 2, c0 = (tid & 3) * 8;
            size_t rowb = ((size_t)b * NT_ + (size_t)kt * 64 + r) * D_ + h * DK_;
#pragma unroll
            for (int j = 0; j < 8; ++j) {
                s_k[r][c0 + j] = Kp[rowb + c0 + j];
                s_v[r][c0 + j] = Vp[rowb + c0 + j];
            }
        }
        __syncthreads();

#pragma unroll 1
        for (int qq = 0; qq < 8; ++qq) {
            int qi = qi0 + qq;
            ull mw = bits[((size_t)b * T_ + qt * 32 + qi) * (NT_ / 64) + kt];
            float s = 0.f;
#pragma unroll
            for (int d = 0; d < DK_; ++d) s += s_q[qi][d] * s_k[lane][d];
            s = ((mw >> lane) & 1ull) ? s * scale : -1e9f;
            float mx = s;
#pragma unroll
            for (int o = 32; o; o >>= 1) mx = fmaxf(mx, __shfl_xor(mx, o, 64));
            float m_old = s_m[qi];
            float m_new = fmaxf(m_old, mx);
            float p = __expf(s - m_new);
            float ps = p;
#pragma unroll
            for (int o = 32; o; o >>= 1) ps += __shfl_xor(ps, o, 64);
            s_p[qi][lane] = p;
            if (lane == 0) {
                float sc = __expf(m_old - m_new);
                s_scale[qi] = sc;
                s_l[qi] = s_l[qi] * sc + ps;
                s_m[qi] = m_new;
            }
        }
        __syncthreads();

        float sc = s_scale[qi_pv];
        cacc[0] *= sc; cacc[1] *= sc; cacc[2] *= sc; cacc[3] *= sc;
        for (int k = 0; k < 64; ++k) {
            float p = s_p[qi_pv][k];
#pragma unroll
            for (int j = 0; j < 4; ++j) cacc[j] += p * s_v[k][d0_pv + j];
        }
    }
    __syncthreads();
    float inv_l = 1.0f / s_l[qi_pv];
    int t = qt * 32 + qi_pv;
    float* orow = ctx_out + ((size_t)b * T_ + t) * D_ + h * DK_ + d0_pv;
#pragma unroll
    for (int j = 0; j < 4; ++j) orow[j] = cacc[j] * inv_l;
}

// ------------------------------------------------ out = xq + ctx@Wo + bo
__global__ __launch_bounds__(256) void out_kernel(
    const float* __restrict__ ctx, const float* __restrict__ xq,
    const float* __restrict__ Wo, const float* __restrict__ bo, float* __restrict__ out) {
    int blk = blockIdx.x;
    int t0 = (blk & 31) * 16;
    int b = blk >> 5;
    int tid = threadIdx.x;
    __shared__ float s_c[16][D_];
    for (int r = 0; r < 16; ++r)
        s_c[r][tid] = ctx[((size_t)b * T_ + t0 + r) * D_ + tid];
    __syncthreads();
    float acc[16];
#pragma unroll
    for (int r = 0; r < 16; ++r) acc[r] = bo[tid];
    for (int e = 0; e < D_; ++e) {
        float w = Wo[e * D_ + tid];
#pragma unroll
        for (int r = 0; r < 16; ++r) acc[r] += s_c[r][e] * w;
    }
    for (int r = 0; r < 16; ++r) {
        size_t off = ((size_t)b * T_ + t0 + r) * D_ + tid;
        out[off] = xq[off] + acc[r];
    }
}

// ---------------------------------------------------------------- launcher
extern "C" void kernel_launch(void* const* d_in, const int* in_sizes, int n_in,
                              void* d_out, int out_size, void* d_ws, size_t ws_size,
                              hipStream_t stream) {
    const float* x = (const float*)d_in[0];
    const float* md = (const float*)d_in[1];
    const float* na = (const float*)d_in[2];
    const float* ea = (const float*)d_in[3];
    const int* mask = (const int*)d_in[4];
    const float* W_ts1 = (const float*)d_in[5];
    const float* b_ts1 = (const float*)d_in[6];
    const float* W_ts2 = (const float*)d_in[7];
    const float* b_ts2 = (const float*)d_in[8];
    const float* W_a1 = (const float*)d_in[9];
    const float* b_a1 = (const float*)d_in[10];
    const float* W_a2 = (const float*)d_in[11];
    const float* b_a2 = (const float*)d_in[12];
    const float* W_e1 = (const float*)d_in[13];
    const float* b_e1 = (const float*)d_in[14];
    const float* W_e2 = (const float*)d_in[15];
    const float* b_e2 = (const float*)d_in[16];
    const float* Wq = (const float*)d_in[17];
    const float* bq = (const float*)d_in[18];
    const float* Wk = (const float*)d_in[19];
    const float* bk = (const float*)d_in[20];
    const float* Wv = (const float*)d_in[21];
    const float* bv = (const float*)d_in[22];
    const float* Wo = (const float*)d_in[23];
    const float* bo = (const float*)d_in[24];
    const float* ln_g = (const float*)d_in[25];
    const float* ln_b = (const float*)d_in[26];
    float* out = (float*)d_out;

    char* ws = (char*)d_ws;
    float* pe = (float*)ws;  ws += (size_t)T_ * D_ * 4;
    ull* bits = (ull*)ws;    ws += (size_t)B_ * T_ * (NT_ / 64) * 8;
    float* Kp = (float*)ws;  ws += (size_t)B_ * NT_ * D_ * 4;
    float* Vp = (float*)ws;  ws += (size_t)B_ * NT_ * D_ * 4;
    float* xq = (float*)ws;  ws += (size_t)B_ * T_ * D_ * 4;
    float* Qp = (float*)ws;  ws += (size_t)B_ * T_ * D_ * 4;
    float* ctx = (float*)ws; ws += (size_t)B_ * T_ * D_ * 4;

    pe_kernel<<<T_, 256, 0, stream>>>(pe);
    maskbits_kernel<<<B_ * T_, 256, 0, stream>>>(mask, bits);
    kv_kernel<<<B_ * N_ * (T_ / 16), 256, 0, stream>>>(
        md, na, ea, W_ts1, b_ts1, W_ts2, b_ts2, W_a1, b_a1, W_a2, b_a2,
        W_e1, b_e1, W_e2, b_e2, Wk, bk, Wv, bv, pe, Kp, Vp);
    q_kernel<<<B_ * (T_ / 16), 256, 0, stream>>>(x, pe, Wq, bq, ln_g, ln_b, xq, Qp);
    attn_kernel<<<B_ * H_ * (T_ / 32), 256, 0, stream>>>(Qp, Kp, Vp, bits, ctx);
    out_kernel<<<B_ * (T_ / 16), 256, 0, stream>>>(ctx, xq, Wo, bo, out);
}

// Round 2
// 596.237 us; speedup vs baseline: 2.6451x; 2.6451x over previous
//
#include <hip/hip_runtime.h>
#include <hip/hip_bf16.h>

#define B_ 4
#define T_ 512
#define N_ 16
#define D_ 256
#define H_ 8
#define DK_ 32
#define NT_ (N_ * T_)
#define CTS_ 6
#define CN_ 4
#define CE_ 3
#define TSE_ 192
#define AUXE_ 64
#define SPLIT_ 4
#define KWORDS_ (NT_ / 64)   // 128 mask words per row

typedef unsigned long long ull;
typedef __bf16 bf16x8 __attribute__((ext_vector_type(8)));
typedef float f32x4 __attribute__((ext_vector_type(4)));

// ---------------------------------------------------------------- PE table
__global__ __launch_bounds__(256) void pe_kernel(float* pe) {
    int t = blockIdx.x;
    int d = threadIdx.x;
    int j = d >> 1;
    float div = expf((float)(2 * j) * (-9.210340371976184f / 256.0f)); // -ln(10000)/D
    float a = (float)t * div;
    pe[t * D_ + d] = (d & 1) ? cosf(a) : sinf(a);
}

// ------------------------------------- mask -> transposed bitmask [B][128][T]
__global__ __launch_bounds__(256) void maskbits_kernel(const int* __restrict__ mask,
                                                       ull* __restrict__ bitsT) {
    int row = blockIdx.x;  // b*T + t
    int b = row >> 9, t = row & (T_ - 1);
    const int* mrow = mask + (size_t)row * NT_;
    int lane = threadIdx.x & 63, wave = threadIdx.x >> 6;
    for (int it = 0; it < NT_ / 256; ++it) {
        int k = it * 256 + wave * 64 + lane;
        ull bal = __ballot(mrow[k] != 0);
        if (lane == 0) bitsT[((size_t)b * KWORDS_ + (k >> 6)) * T_ + t] = bal;
    }
}

// ------------------- KV build + K/V projection -> bf16 Kb [bh][key][32], Vt [bh][d][NT]
__global__ __launch_bounds__(256) void kv_kernel(
    const float* __restrict__ md, const float* __restrict__ na, const float* __restrict__ ea,
    const float* __restrict__ W_ts1, const float* __restrict__ b_ts1,
    const float* __restrict__ W_ts2, const float* __restrict__ b_ts2,
    const float* __restrict__ W_a1, const float* __restrict__ b_a1,
    const float* __restrict__ W_a2, const float* __restrict__ b_a2,
    const float* __restrict__ W_e1, const float* __restrict__ b_e1,
    const float* __restrict__ W_e2, const float* __restrict__ b_e2,
    const float* __restrict__ Wk, const float* __restrict__ bk,
    const float* __restrict__ Wv, const float* __restrict__ bv,
    const float* __restrict__ pe, __bf16* __restrict__ Kb, __bf16* __restrict__ Vt) {
    int blk = blockIdx.x;
    int t0 = (blk & 31) * 16;
    int n = (blk >> 5) & 15;
    int b = blk >> 9;
    int tid = threadIdx.x;

    __shared__ float s_in[CTS_ + CN_ + CE_][16];
    __shared__ float s_hts[16][TSE_];
    __shared__ float s_haux[16][AUXE_];
    __shared__ float s_hedge[16][D_];
    __shared__ float s_key[16][D_];
    __shared__ float s_val[16][D_];

    if (tid < (CTS_ + CN_ + CE_) * 16) {
        int c = tid >> 4, r = tid & 15;
        int t = t0 + r;
        float v;
        if (c < CTS_)
            v = md[(((size_t)b * N_ + n) * CTS_ + c) * T_ + t];
        else if (c < CTS_ + CN_)
            v = na[(((size_t)b * N_ + n) * CN_ + (c - CTS_)) * T_ + t];
        else
            v = ea[(((size_t)b * N_ + n) * CE_ + (c - CTS_ - CN_)) * T_ + t];
        s_in[c][r] = v;
    }
    __syncthreads();

    if (tid < TSE_) {
        for (int r = 0; r < 16; ++r) {
            float acc = b_ts1[tid];
#pragma unroll
            for (int c = 0; c < CTS_; ++c) acc += s_in[c][r] * W_ts1[c * TSE_ + tid];
            s_hts[r][tid] = fmaxf(acc, 0.f);
        }
    }
    if (tid < AUXE_) {
        for (int r = 0; r < 16; ++r) {
            float acc = b_a1[tid];
#pragma unroll
            for (int c = 0; c < CN_; ++c) acc += s_in[CTS_ + c][r] * W_a1[c * AUXE_ + tid];
            s_haux[r][tid] = fmaxf(acc, 0.f);
        }
    }
    {
        for (int r = 0; r < 16; ++r) {
            float acc = b_e1[tid];
#pragma unroll
            for (int c = 0; c < CE_; ++c) acc += s_in[CTS_ + CN_ + c][r] * W_e1[c * D_ + tid];
            s_hedge[r][tid] = fmaxf(acc, 0.f);
        }
    }
    __syncthreads();

    float nbr[16], edg[16];
    if (tid < TSE_) {
#pragma unroll
        for (int r = 0; r < 16; ++r) nbr[r] = b_ts2[tid];
        for (int e = 0; e < TSE_; ++e) {
            float w = W_ts2[e * TSE_ + tid];
#pragma unroll
            for (int r = 0; r < 16; ++r) nbr[r] += s_hts[r][e] * w;
        }
    } else {
        int d2 = tid - TSE_;
#pragma unroll
        for (int r = 0; r < 16; ++r) nbr[r] = b_a2[d2];
        for (int e = 0; e < AUXE_; ++e) {
            float w = W_a2[e * AUXE_ + d2];
#pragma unroll
            for (int r = 0; r < 16; ++r) nbr[r] += s_haux[r][e] * w;
        }
    }
    {
#pragma unroll
        for (int r = 0; r < 16; ++r) edg[r] = b_e2[tid];
        for (int e = 0; e < D_; ++e) {
            float w = W_e2[e * D_ + tid];
#pragma unroll
            for (int r = 0; r < 16; ++r) edg[r] += s_hedge[r][e] * w;
        }
    }
    for (int r = 0; r < 16; ++r) {
        int t = t0 + r;
        float p = pe[t * D_ + tid];
        s_key[r][tid] = nbr[r] * edg[r] + p;
        s_val[r][tid] = nbr[r] + p;
    }
    __syncthreads();

    float kacc[16], vacc[16];
#pragma unroll
    for (int r = 0; r < 16; ++r) {
        kacc[r] = bk[tid];
        vacc[r] = bv[tid];
    }
    for (int e = 0; e < D_; ++e) {
        float wk = Wk[e * D_ + tid];
        float wv = Wv[e * D_ + tid];
#pragma unroll
        for (int r = 0; r < 16; ++r) {
            kacc[r] += s_key[r][e] * wk;
            vacc[r] += s_val[r][e] * wv;
        }
    }
    // write bf16, attention-friendly layouts
    int hh = tid >> 5, dd = tid & 31;
    size_t key0 = (size_t)n * T_ + t0;
    size_t bh = (size_t)b * H_ + hh;
    for (int r = 0; r < 16; ++r) {
        Kb[(bh * NT_ + key0 + r) * DK_ + dd] = (__bf16)kacc[r];
        Vt[(bh * DK_ + dd) * NT_ + key0 + r] = (__bf16)vacc[r];
    }
}

// -------------------------- xq = x + pe, LayerNorm, Q proj -> bf16 Qb [b][t][256]
__global__ __launch_bounds__(256) void q_kernel(
    const float* __restrict__ x, const float* __restrict__ pe,
    const float* __restrict__ Wq, const float* __restrict__ bq,
    const float* __restrict__ ln_g, const float* __restrict__ ln_b,
    float* __restrict__ xq, __bf16* __restrict__ Qb) {
    int blk = blockIdx.x;
    int t0 = (blk & 31) * 16;
    int b = blk >> 5;
    int tid = threadIdx.x;

    __shared__ float s_xn[16][D_];
    __shared__ float s_red[8];

    for (int r = 0; r < 16; ++r) {
        int t = t0 + r;
        size_t off = ((size_t)b * T_ + t) * D_ + tid;
        float v = x[off] + pe[t * D_ + tid];
        xq[off] = v;
        float s1 = v, s2 = v * v;
#pragma unroll
        for (int o = 32; o; o >>= 1) {
            s1 += __shfl_down(s1, o, 64);
            s2 += __shfl_down(s2, o, 64);
        }
        if ((tid & 63) == 0) {
            s_red[tid >> 6] = s1;
            s_red[4 + (tid >> 6)] = s2;
        }
        __syncthreads();
        float t1 = s_red[0] + s_red[1] + s_red[2] + s_red[3];
        float t2 = s_red[4] + s_red[5] + s_red[6] + s_red[7];
        float mu = t1 * (1.f / D_);
        float var = t2 * (1.f / D_) - mu * mu;
        float rs = rsqrtf(var + 1e-6f);
        s_xn[r][tid] = (v - mu) * rs * ln_g[tid] + ln_b[tid];
        __syncthreads();
    }

    float acc[16];
#pragma unroll
    for (int r = 0; r < 16; ++r) acc[r] = bq[tid];
    for (int e = 0; e < D_; ++e) {
        float w = Wq[e * D_ + tid];
#pragma unroll
        for (int r = 0; r < 16; ++r) acc[r] += s_xn[r][e] * w;
    }
    for (int r = 0; r < 16; ++r) {
        Qb[((size_t)b * T_ + t0 + r) * D_ + tid] = (__bf16)acc[r];
    }
}

// ----------------------------------- MFMA flash attention, split-K partials
// grid: B*H*(T/64)*SPLIT = 1024 blocks, 256 threads (4 waves x 16 queries)
__global__ __launch_bounds__(256) void attn_mfma_kernel(
    const __bf16* __restrict__ Qb, const __bf16* __restrict__ Kb,
    const __bf16* __restrict__ Vt, const ull* __restrict__ bitsT,
    float* __restrict__ Opart, float* __restrict__ Mpart, float* __restrict__ Lpart) {
    int blk = blockIdx.x;
    int kh = blk & (SPLIT_ - 1);
    int qt = (blk >> 2) & 7;
    int h = (blk >> 5) & 7;
    int b = blk >> 8;
    int tid = threadIdx.x, lane = tid & 63, w = tid >> 6;
    int lg = lane >> 4, lr = lane & 15;

    __shared__ __align__(16) __bf16 sK[64 * 32];        // chunk-swizzled rows of 64B
    __shared__ __align__(16) __bf16 sV[32 * 64];        // vt rows of 128B, chunk-swizzled
    __shared__ __align__(16) __bf16 sP[4 * 16 * 72];    // per-wave P, stride 72
    __shared__ ull s_mb[64];

    const size_t bh = (size_t)b * H_ + h;
    const __bf16* Kbase = Kb + bh * NT_ * DK_;
    const __bf16* Vbase = Vt + bh * DK_ * NT_;

    // constant Q fragment: lane holds Q[qrow][lg*8 .. +8]
    int qrow = qt * 64 + w * 16 + lr;
    bf16x8 qfrag = *(const bf16x8*)(Qb + ((size_t)b * T_ + qrow) * D_ + h * DK_ + lg * 8);

    float m_run[4], l_run[4];
    f32x4 acc0 = {0.f, 0.f, 0.f, 0.f}, acc1 = {0.f, 0.f, 0.f, 0.f};
#pragma unroll
    for (int r = 0; r < 4; ++r) { m_run[r] = -1e30f; l_run[r] = 0.f; }
    const float scale = 0.1767766952966369f;  // 1/sqrt(32)

    // staging coords
    int krow = tid >> 2, kgl = tid & 3;              // K: row, dest chunk
    int vd = tid >> 3, vsl = tid & 7;                // V: d-row, dest chunk

#pragma unroll 1
    for (int kt = 0; kt < KWORDS_ / SPLIT_; ++kt) {
        int ktg = kh * (KWORDS_ / SPLIT_) + kt;
        int k0 = ktg * 64;
        __syncthreads();
        // stage K tile (swizzle dest chunk), V tile, mask words
        {
            bf16x8 kc = *(const bf16x8*)(Kbase + (size_t)(k0 + krow) * DK_ + kgl * 8);
            *(bf16x8*)(sK + krow * 32 + ((kgl ^ (krow & 3)) * 8)) = kc;
            bf16x8 vc = *(const bf16x8*)(Vbase + (size_t)vd * NT_ + k0 + vsl * 8);
            *(bf16x8*)(sV + vd * 64 + ((vsl ^ (vd & 7)) * 8)) = vc;
            if (tid < 64) s_mb[tid] = bitsT[((size_t)b * KWORDS_ + ktg) * T_ + qt * 64 + tid];
        }
        __syncthreads();

        // ---- QK^T: 4 MFMAs, S[q=(lg*4+reg)][key=sub*16+lr]
        f32x4 s4[4];
#pragma unroll
        for (int sub = 0; sub < 4; ++sub) {
            int row = sub * 16 + lr;
            bf16x8 kf = *(const bf16x8*)(sK + row * 32 + ((lg ^ (row & 3)) * 8));
            f32x4 z = {0.f, 0.f, 0.f, 0.f};
            s4[sub] = __builtin_amdgcn_mfma_f32_16x16x32_bf16(qfrag, kf, z, 0, 0, 0);
        }

        // ---- masked online softmax
        ull mw[4];
#pragma unroll
        for (int r = 0; r < 4; ++r) mw[r] = s_mb[w * 16 + lg * 4 + r] >> lr;
        float sv[4][4];
#pragma unroll
        for (int sub = 0; sub < 4; ++sub)
#pragma unroll
            for (int r = 0; r < 4; ++r) {
                bool on = (mw[r] >> (sub * 16)) & 1ull;
                sv[sub][r] = on ? s4[sub][r] * scale : -1e30f;
            }
        float mx[4];
#pragma unroll
        for (int r = 0; r < 4; ++r)
            mx[r] = fmaxf(fmaxf(sv[0][r], sv[1][r]), fmaxf(sv[2][r], sv[3][r]));
#pragma unroll
        for (int o = 1; o <= 8; o <<= 1)
#pragma unroll
            for (int r = 0; r < 4; ++r) mx[r] = fmaxf(mx[r], __shfl_xor(mx[r], o, 64));
        float sc[4], mnew[4];
#pragma unroll
        for (int r = 0; r < 4; ++r) {
            float mn = fmaxf(m_run[r], mx[r]);
            sc[r] = __expf(m_run[r] - mn);
            mnew[r] = mn;
            m_run[r] = mn;
        }
        float p[4][4], psum[4] = {0.f, 0.f, 0.f, 0.f};
#pragma unroll
        for (int sub = 0; sub < 4; ++sub)
#pragma unroll
            for (int r = 0; r < 4; ++r) {
                float pv = (sv[sub][r] > -1e29f) ? __expf(sv[sub][r] - mnew[r]) : 0.f;
                p[sub][r] = pv;
                psum[r] += pv;
            }
#pragma unroll
        for (int o = 1; o <= 8; o <<= 1)
#pragma unroll
            for (int r = 0; r < 4; ++r) psum[r] += __shfl_xor(psum[r], o, 64);
#pragma unroll
        for (int r = 0; r < 4; ++r) {
            l_run[r] = l_run[r] * sc[r] + psum[r];
            acc0[r] *= sc[r];
            acc1[r] *= sc[r];
        }
        // write P (bf16) to per-wave LDS
#pragma unroll
        for (int sub = 0; sub < 4; ++sub)
#pragma unroll
            for (int r = 0; r < 4; ++r)
                sP[w * 1152 + (lg * 4 + r) * 72 + sub * 16 + lr] = (__bf16)p[sub][r];

        // ---- PV: O[q][d] += P[q][k] V[k][d]
#pragma unroll
        for (int kstep = 0; kstep < 2; ++kstep) {
            bf16x8 pa = *(const bf16x8*)(sP + w * 1152 + lr * 72 + kstep * 32 + lg * 8);
            {
                int d = lr;
                bf16x8 vf = *(const bf16x8*)(sV + d * 64 + (((kstep * 4 + lg) ^ (d & 7)) * 8));
                acc0 = __builtin_amdgcn_mfma_f32_16x16x32_bf16(pa, vf, acc0, 0, 0, 0);
            }
            {
                int d = 16 + lr;
                bf16x8 vf = *(const bf16x8*)(sV + d * 64 + (((kstep * 4 + lg) ^ (d & 7)) * 8));
                acc1 = __builtin_amdgcn_mfma_f32_16x16x32_bf16(pa, vf, acc1, 0, 0, 0);
            }
        }
    }

    // ---- write partials (unnormalized O, running m/l)
    size_t obase = (((size_t)kh * B_ + b) * H_ + h) * T_ + qt * 64;
    int qloc = w * 16 + lg * 4;
#pragma unroll
    for (int r = 0; r < 4; ++r) {
        Opart[(obase + qloc + r) * DK_ + lr] = acc0[r];
        Opart[(obase + qloc + r) * DK_ + 16 + lr] = acc1[r];
    }
    if (lr == 0) {
#pragma unroll
        for (int r = 0; r < 4; ++r) {
            Mpart[obase + qloc + r] = m_run[r];
            Lpart[obase + qloc + r] = l_run[r];
        }
    }
}

// ------------------------------------------------ merge split-K partials -> ctx f32
__global__ __launch_bounds__(256) void merge_kernel(
    const float* __restrict__ Opart, const float* __restrict__ Mpart,
    const float* __restrict__ Lpart, float* __restrict__ ctx) {
    int idx = blockIdx.x * 256 + threadIdx.x;  // B*H*T*32 total
    int d = idx & 31;
    int t = (idx >> 5) & (T_ - 1);
    int bh = idx >> 14;
    int h = bh & 7, b = bh >> 3;
    size_t ps = (size_t)B_ * H_ * T_;
    size_t base = (size_t)bh * T_ + t;
    float m0 = Mpart[base], m1 = Mpart[ps + base], m2 = Mpart[2 * ps + base], m3 = Mpart[3 * ps + base];
    float M = fmaxf(fmaxf(m0, m1), fmaxf(m2, m3));
    float w0 = __expf(m0 - M), w1 = __expf(m1 - M), w2 = __expf(m2 - M), w3 = __expf(m3 - M);
    float L = w0 * Lpart[base] + w1 * Lpart[ps + base] + w2 * Lpart[2 * ps + base] + w3 * Lpart[3 * ps + base];
    float o = w0 * Opart[base * DK_ + d] + w1 * Opart[(ps + base) * DK_ + d] +
              w2 * Opart[(2 * ps + base) * DK_ + d] + w3 * Opart[(3 * ps + base) * DK_ + d];
    ctx[((size_t)b * T_ + t) * D_ + h * DK_ + d] = o / L;
}

// ------------------------------------------------ out = xq + ctx@Wo + bo
__global__ __launch_bounds__(256) void out_kernel(
    const float* __restrict__ ctx, const float* __restrict__ xq,
    const float* __restrict__ Wo, const float* __restrict__ bo, float* __restrict__ out) {
    int blk = blockIdx.x;
    int t0 = (blk & 31) * 16;
    int b = blk >> 5;
    int tid = threadIdx.x;
    __shared__ float s_c[16][D_];
    for (int r = 0; r < 16; ++r)
        s_c[r][tid] = ctx[((size_t)b * T_ + t0 + r) * D_ + tid];
    __syncthreads();
    float acc[16];
#pragma unroll
    for (int r = 0; r < 16; ++r) acc[r] = bo[tid];
    for (int e = 0; e < D_; ++e) {
        float w = Wo[e * D_ + tid];
#pragma unroll
        for (int r = 0; r < 16; ++r) acc[r] += s_c[r][e] * w;
    }
    for (int r = 0; r < 16; ++r) {
        size_t off = ((size_t)b * T_ + t0 + r) * D_ + tid;
        out[off] = xq[off] + acc[r];
    }
}

// ---------------------------------------------------------------- launcher
extern "C" void kernel_launch(void* const* d_in, const int* in_sizes, int n_in,
                              void* d_out, int out_size, void* d_ws, size_t ws_size,
                              hipStream_t stream) {
    const float* x = (const float*)d_in[0];
    const float* md = (const float*)d_in[1];
    const float* na = (const float*)d_in[2];
    const float* ea = (const float*)d_in[3];
    const int* mask = (const int*)d_in[4];
    const float* W_ts1 = (const float*)d_in[5];
    const float* b_ts1 = (const float*)d_in[6];
    const float* W_ts2 = (const float*)d_in[7];
    const float* b_ts2 = (const float*)d_in[8];
    const float* W_a1 = (const float*)d_in[9];
    const float* b_a1 = (const float*)d_in[10];
    const float* W_a2 = (const float*)d_in[11];
    const float* b_a2 = (const float*)d_in[12];
    const float* W_e1 = (const float*)d_in[13];
    const float* b_e1 = (const float*)d_in[14];
    const float* W_e2 = (const float*)d_in[15];
    const float* b_e2 = (const float*)d_in[16];
    const float* Wq = (const float*)d_in[17];
    const float* bq = (const float*)d_in[18];
    const float* Wk = (const float*)d_in[19];
    const float* bk = (const float*)d_in[20];
    const float* Wv = (const float*)d_in[21];
    const float* bv = (const float*)d_in[22];
    const float* Wo = (const float*)d_in[23];
    const float* bo = (const float*)d_in[24];
    const float* ln_g = (const float*)d_in[25];
    const float* ln_b = (const float*)d_in[26];
    float* out = (float*)d_out;

    char* ws = (char*)d_ws;
    float* pe = (float*)ws;    ws += (size_t)T_ * D_ * 4;                      // 512 KB
    ull* bitsT = (ull*)ws;     ws += (size_t)B_ * KWORDS_ * T_ * 8;            // 2 MB
    __bf16* Kb = (__bf16*)ws;  ws += (size_t)B_ * H_ * NT_ * DK_ * 2;          // 16 MB
    __bf16* Vt = (__bf16*)ws;  ws += (size_t)B_ * H_ * DK_ * NT_ * 2;          // 16 MB
    float* xq = (float*)ws;    ws += (size_t)B_ * T_ * D_ * 4;                 // 2 MB
    __bf16* Qb = (__bf16*)ws;  ws += (size_t)B_ * T_ * D_ * 2;                 // 1 MB
    float* ctx = (float*)ws;   ws += (size_t)B_ * T_ * D_ * 4;                 // 2 MB
    float* Opart = (float*)ws; ws += (size_t)SPLIT_ * B_ * H_ * T_ * DK_ * 4;  // 8 MB
    float* Mpart = (float*)ws; ws += (size_t)SPLIT_ * B_ * H_ * T_ * 4;        // 256 KB
    float* Lpart = (float*)ws; ws += (size_t)SPLIT_ * B_ * H_ * T_ * 4;        // 256 KB

    pe_kernel<<<T_, 256, 0, stream>>>(pe);
    maskbits_kernel<<<B_ * T_, 256, 0, stream>>>(mask, bitsT);
    kv_kernel<<<B_ * N_ * (T_ / 16), 256, 0, stream>>>(
        md, na, ea, W_ts1, b_ts1, W_ts2, b_ts2, W_a1, b_a1, W_a2, b_a2,
        W_e1, b_e1, W_e2, b_e2, Wk, bk, Wv, bv, pe, Kb, Vt);
    q_kernel<<<B_ * (T_ / 16), 256, 0, stream>>>(x, pe, Wq, bq, ln_g, ln_b, xq, Qb);
    attn_mfma_kernel<<<B_ * H_ * (T_ / 64) * SPLIT_, 256, 0, stream>>>(
        Qb, Kb, Vt, bitsT, Opart, Mpart, Lpart);
    merge_kernel<<<(B_ * H_ * T_ * DK_) / 256, 256, 0, stream>>>(Opart, Mpart, Lpart, ctx);
    out_kernel<<<B_ * (T_ / 16), 256, 0, stream>>>(ctx, xq, Wo, bo, out);
}

// Round 3
// 303.654 us; speedup vs baseline: 5.1938x; 1.9635x over previous
//
#include <hip/hip_runtime.h>
#include <hip/hip_bf16.h>

#define B_ 4
#define T_ 512
#define N_ 16
#define D_ 256
#define H_ 8
#define DK_ 32
#define NT_ (N_ * T_)
#define CTS_ 6
#define CN_ 4
#define CE_ 3
#define TSE_ 192
#define AUXE_ 64
#define SPLIT_ 4
#define KWORDS_ (NT_ / 64)   // 128 mask words per row

typedef unsigned long long ull;
typedef __bf16 bf16x8 __attribute__((ext_vector_type(8)));
typedef float f32x4 __attribute__((ext_vector_type(4)));

// ---------------------------------------------------------------- PE table
__global__ __launch_bounds__(256) void pe_kernel(float* pe) {
    int t = blockIdx.x;
    int d = threadIdx.x;
    int j = d >> 1;
    float div = expf((float)(2 * j) * (-9.210340371976184f / 256.0f)); // -ln(10000)/D
    float a = (float)t * div;
    pe[t * D_ + d] = (d & 1) ? cosf(a) : sinf(a);
}

// ------------------------------------- mask -> transposed bitmask [B][128][T]
__global__ __launch_bounds__(256) void maskbits_kernel(const int* __restrict__ mask,
                                                       ull* __restrict__ bitsT) {
    int row = blockIdx.x;  // b*T + t
    int b = row >> 9, t = row & (T_ - 1);
    const int* mrow = mask + (size_t)row * NT_;
    int lane = threadIdx.x & 63, wave = threadIdx.x >> 6;
    for (int it = 0; it < NT_ / 256; ++it) {
        int k = it * 256 + wave * 64 + lane;
        ull bal = __ballot(mrow[k] != 0);
        if (lane == 0) bitsT[((size_t)b * KWORDS_ + (k >> 6)) * T_ + t] = bal;
    }
}

// -------------------------------- weight prep: bf16, [col][k] layouts, padded
// sizes: ts1P 6144, a1P 2048, e1P 8192, ts2T 36864, a2T 4096, e2T 65536,
//        WkT 65536, WvT 65536  -> total 253952 elems, grid 992*256
__global__ __launch_bounds__(256) void wprep_kernel(
    const float* __restrict__ W_ts1, const float* __restrict__ W_a1,
    const float* __restrict__ W_e1, const float* __restrict__ W_ts2,
    const float* __restrict__ W_a2, const float* __restrict__ W_e2,
    const float* __restrict__ Wk, const float* __restrict__ Wv,
    __bf16* __restrict__ ts1P, __bf16* __restrict__ a1P, __bf16* __restrict__ e1P,
    __bf16* __restrict__ ts2T, __bf16* __restrict__ a2T, __bf16* __restrict__ e2T,
    __bf16* __restrict__ WkT, __bf16* __restrict__ WvT) {
    int i = blockIdx.x * 256 + threadIdx.x;
    if (i < 6144) { int col = i >> 5, k = i & 31;
        ts1P[i] = (__bf16)(k < 6 ? W_ts1[k * TSE_ + col] : 0.f); return; }
    i -= 6144;
    if (i < 2048) { int col = i >> 5, k = i & 31;
        a1P[i] = (__bf16)((k >= 6 && k < 10) ? W_a1[(k - 6) * AUXE_ + col] : 0.f); return; }
    i -= 2048;
    if (i < 8192) { int col = i >> 5, k = i & 31;
        e1P[i] = (__bf16)((k >= 10 && k < 13) ? W_e1[(k - 10) * D_ + col] : 0.f); return; }
    i -= 8192;
    if (i < 36864) { int col = i / 192, k = i % 192;
        ts2T[i] = (__bf16)W_ts2[k * TSE_ + col]; return; }
    i -= 36864;
    if (i < 4096) { int col = i >> 6, k = i & 63;
        a2T[i] = (__bf16)W_a2[k * AUXE_ + col]; return; }
    i -= 4096;
    if (i < 65536) { int col = i >> 8, k = i & 255;
        e2T[i] = (__bf16)W_e2[k * D_ + col]; return; }
    i -= 65536;
    if (i < 65536) { int col = i >> 8, k = i & 255;
        WkT[i] = (__bf16)Wk[k * D_ + col]; return; }
    i -= 65536;
    { int col = i >> 8, k = i & 255; WvT[i] = (__bf16)Wv[k * D_ + col]; }
}

// ------------------------- MFMA kv chain: 64 rows/block, 4 waves x 16-row tiles
__global__ __launch_bounds__(256, 2) void kv_mfma_kernel(
    const float* __restrict__ md, const float* __restrict__ na, const float* __restrict__ ea,
    const __bf16* __restrict__ ts1P, const __bf16* __restrict__ a1P,
    const __bf16* __restrict__ e1P,
    const float* __restrict__ b_ts1, const float* __restrict__ b_a1,
    const float* __restrict__ b_e1,
    const __bf16* __restrict__ ts2T, const __bf16* __restrict__ a2T,
    const __bf16* __restrict__ e2T,
    const float* __restrict__ b_ts2, const float* __restrict__ b_a2,
    const float* __restrict__ b_e2,
    const __bf16* __restrict__ WkT, const float* __restrict__ bk,
    const __bf16* __restrict__ WvT, const float* __restrict__ bv,
    const float* __restrict__ pe, __bf16* __restrict__ Kb, __bf16* __restrict__ Vt) {
    int blk = blockIdx.x;          // 4b * 16n * 8t = 512
    int t0 = (blk & 7) * 64;
    int n = (blk >> 3) & 15;
    int b = blk >> 7;
    int tid = threadIdx.x, lane = tid & 63, w = tid >> 6;
    int lr = lane & 15, lg = lane >> 4;

    __shared__ __bf16 sA[64 * 40];      // A_all: 13 channels + zero pad to K=32
    __shared__ __bf16 sU[34304];        // union: {hts,haux,hedge} then {skey,sval}
    __bf16* hts = sU;                   // [64][200]
    __bf16* haux = sU + 12800;          // [64][72]
    __bf16* hedge = sU + 17408;         // [64][264]
    __bf16* skey = sU;                  // [64][264]
    __bf16* sval = sU + 16896;          // [64][264]

    for (int i = tid; i < 64 * 40; i += 256) sA[i] = (__bf16)0.f;
    __syncthreads();
    {
        int t = tid & 63, cg = tid >> 6;
        size_t bn = (size_t)b * N_ + n;
        for (int c = cg; c < 13; c += 4) {
            float v;
            if (c < 6) v = md[(bn * CTS_ + c) * T_ + t0 + t];
            else if (c < 10) v = na[(bn * CN_ + (c - 6)) * T_ + t0 + t];
            else v = ea[(bn * CE_ + (c - 10)) * T_ + t0 + t];
            sA[t * 40 + c] = (__bf16)v;
        }
    }
    __syncthreads();

    int arow = w * 16 + lr;       // A-fragment row
    int crow = w * 16 + lg * 4;   // C-fragment row base (+reg)
    bf16x8 afrag1 = *(const bf16x8*)(sA + arow * 40 + lg * 8);

    // ---- phase 2: first layers (K=32, one MFMA per col-tile), ReLU, store bf16
#pragma unroll
    for (int ct = 0; ct < 12; ++ct) {
        int gcol = ct * 16 + lr;
        bf16x8 bf = *(const bf16x8*)(ts1P + gcol * 32 + lg * 8);
        f32x4 z = {0.f, 0.f, 0.f, 0.f};
        f32x4 c = __builtin_amdgcn_mfma_f32_16x16x32_bf16(afrag1, bf, z, 0, 0, 0);
        float bias = b_ts1[gcol];
#pragma unroll
        for (int r = 0; r < 4; ++r) hts[(crow + r) * 200 + gcol] = (__bf16)fmaxf(c[r] + bias, 0.f);
    }
#pragma unroll
    for (int ct = 0; ct < 4; ++ct) {
        int gcol = ct * 16 + lr;
        bf16x8 bf = *(const bf16x8*)(a1P + gcol * 32 + lg * 8);
        f32x4 z = {0.f, 0.f, 0.f, 0.f};
        f32x4 c = __builtin_amdgcn_mfma_f32_16x16x32_bf16(afrag1, bf, z, 0, 0, 0);
        float bias = b_a1[gcol];
#pragma unroll
        for (int r = 0; r < 4; ++r) haux[(crow + r) * 72 + gcol] = (__bf16)fmaxf(c[r] + bias, 0.f);
    }
#pragma unroll
    for (int ct = 0; ct < 16; ++ct) {
        int gcol = ct * 16 + lr;
        bf16x8 bf = *(const bf16x8*)(e1P + gcol * 32 + lg * 8);
        f32x4 z = {0.f, 0.f, 0.f, 0.f};
        f32x4 c = __builtin_amdgcn_mfma_f32_16x16x32_bf16(afrag1, bf, z, 0, 0, 0);
        float bias = b_e1[gcol];
#pragma unroll
        for (int r = 0; r < 4; ++r) hedge[(crow + r) * 264 + gcol] = (__bf16)fmaxf(c[r] + bias, 0.f);
    }
    __syncthreads();

    // ---- phase 3: nbr (ts2|a2) and edg (e2) accumulators in registers
    f32x4 nacc[16], eacc[16];
#pragma unroll
    for (int ct = 0; ct < 16; ++ct) {
        nacc[ct] = (f32x4){0.f, 0.f, 0.f, 0.f};
        eacc[ct] = (f32x4){0.f, 0.f, 0.f, 0.f};
    }
#pragma unroll
    for (int ks = 0; ks < 8; ++ks) {
        bf16x8 af = *(const bf16x8*)(hedge + arow * 264 + ks * 32 + lg * 8);
#pragma unroll
        for (int ct = 0; ct < 16; ++ct) {
            bf16x8 bf = *(const bf16x8*)(e2T + (ct * 16 + lr) * 256 + ks * 32 + lg * 8);
            eacc[ct] = __builtin_amdgcn_mfma_f32_16x16x32_bf16(af, bf, eacc[ct], 0, 0, 0);
        }
    }
#pragma unroll
    for (int ks = 0; ks < 6; ++ks) {
        bf16x8 af = *(const bf16x8*)(hts + arow * 200 + ks * 32 + lg * 8);
#pragma unroll
        for (int ct = 0; ct < 12; ++ct) {
            bf16x8 bf = *(const bf16x8*)(ts2T + (ct * 16 + lr) * 192 + ks * 32 + lg * 8);
            nacc[ct] = __builtin_amdgcn_mfma_f32_16x16x32_bf16(af, bf, nacc[ct], 0, 0, 0);
        }
    }
#pragma unroll
    for (int ks = 0; ks < 2; ++ks) {
        bf16x8 af = *(const bf16x8*)(haux + arow * 72 + ks * 32 + lg * 8);
#pragma unroll
        for (int ct = 0; ct < 4; ++ct) {
            bf16x8 bf = *(const bf16x8*)(a2T + (ct * 16 + lr) * 64 + ks * 32 + lg * 8);
            nacc[12 + ct] = __builtin_amdgcn_mfma_f32_16x16x32_bf16(af, bf, nacc[12 + ct], 0, 0, 0);
        }
    }
    __syncthreads();   // hts/haux/hedge reads done; safe to overwrite union

    // ---- phase 3b: key = nbr*edg + pe, val = nbr + pe (bf16 into LDS)
#pragma unroll
    for (int ct = 0; ct < 16; ++ct) {
        int gcol = ct * 16 + lr;
        float nb_bias = (ct < 12) ? b_ts2[gcol] : b_a2[gcol - 192];
        float ed_bias = b_e2[gcol];
#pragma unroll
        for (int r = 0; r < 4; ++r) {
            int row = crow + r;
            float p = pe[(t0 + row) * D_ + gcol];
            float nb = nacc[ct][r] + nb_bias;
            float ed = eacc[ct][r] + ed_bias;
            skey[row * 264 + gcol] = (__bf16)(nb * ed + p);
            sval[row * 264 + gcol] = (__bf16)(nb + p);
        }
    }
    __syncthreads();

    // ---- phase 4: K/V projections (K=256 -> 8 ksteps per col-tile)
    size_t key0 = (size_t)n * T_ + t0;
#pragma unroll 1
    for (int ct = 0; ct < 16; ++ct) {
        int gcol = ct * 16 + lr;
        f32x4 ka = {0.f, 0.f, 0.f, 0.f}, va = {0.f, 0.f, 0.f, 0.f};
#pragma unroll
        for (int ks = 0; ks < 8; ++ks) {
            bf16x8 afk = *(const bf16x8*)(skey + arow * 264 + ks * 32 + lg * 8);
            bf16x8 afv = *(const bf16x8*)(sval + arow * 264 + ks * 32 + lg * 8);
            bf16x8 b8k = *(const bf16x8*)(WkT + gcol * 256 + ks * 32 + lg * 8);
            bf16x8 b8v = *(const bf16x8*)(WvT + gcol * 256 + ks * 32 + lg * 8);
            ka = __builtin_amdgcn_mfma_f32_16x16x32_bf16(afk, b8k, ka, 0, 0, 0);
            va = __builtin_amdgcn_mfma_f32_16x16x32_bf16(afv, b8v, va, 0, 0, 0);
        }
        float kbias = bk[gcol], vbias = bv[gcol];
        int h = gcol >> 5, dd = gcol & 31;
        size_t bh = (size_t)b * H_ + h;
#pragma unroll
        for (int r = 0; r < 4; ++r)
            Kb[(bh * NT_ + key0 + crow + r) * DK_ + dd] = (__bf16)(ka[r] + kbias);
        __bf16 tmp[4];
#pragma unroll
        for (int r = 0; r < 4; ++r) tmp[r] = (__bf16)(va[r] + vbias);
        *(ushort4*)(Vt + (bh * DK_ + dd) * NT_ + key0 + crow) = *(ushort4*)tmp;
    }
}

// -------------------------- xq = x + pe, LayerNorm, Q proj -> bf16 Qb [b][t][256]
__global__ __launch_bounds__(256) void q_kernel(
    const float* __restrict__ x, const float* __restrict__ pe,
    const float* __restrict__ Wq, const float* __restrict__ bq,
    const float* __restrict__ ln_g, const float* __restrict__ ln_b,
    float* __restrict__ xq, __bf16* __restrict__ Qb) {
    int blk = blockIdx.x;
    int t0 = (blk & 31) * 16;
    int b = blk >> 5;
    int tid = threadIdx.x;

    __shared__ float s_xn[16][D_];
    __shared__ float s_red[8];

    for (int r = 0; r < 16; ++r) {
        int t = t0 + r;
        size_t off = ((size_t)b * T_ + t) * D_ + tid;
        float v = x[off] + pe[t * D_ + tid];
        xq[off] = v;
        float s1 = v, s2 = v * v;
#pragma unroll
        for (int o = 32; o; o >>= 1) {
            s1 += __shfl_down(s1, o, 64);
            s2 += __shfl_down(s2, o, 64);
        }
        if ((tid & 63) == 0) {
            s_red[tid >> 6] = s1;
            s_red[4 + (tid >> 6)] = s2;
        }
        __syncthreads();
        float t1 = s_red[0] + s_red[1] + s_red[2] + s_red[3];
        float t2 = s_red[4] + s_red[5] + s_red[6] + s_red[7];
        float mu = t1 * (1.f / D_);
        float var = t2 * (1.f / D_) - mu * mu;
        float rs = rsqrtf(var + 1e-6f);
        s_xn[r][tid] = (v - mu) * rs * ln_g[tid] + ln_b[tid];
        __syncthreads();
    }

    float acc[16];
#pragma unroll
    for (int r = 0; r < 16; ++r) acc[r] = bq[tid];
    for (int e = 0; e < D_; ++e) {
        float w = Wq[e * D_ + tid];
#pragma unroll
        for (int r = 0; r < 16; ++r) acc[r] += s_xn[r][e] * w;
    }
    for (int r = 0; r < 16; ++r) {
        Qb[((size_t)b * T_ + t0 + r) * D_ + tid] = (__bf16)acc[r];
    }
}

// ----------------------------------- MFMA flash attention, split-K partials
__global__ __launch_bounds__(256) void attn_mfma_kernel(
    const __bf16* __restrict__ Qb, const __bf16* __restrict__ Kb,
    const __bf16* __restrict__ Vt, const ull* __restrict__ bitsT,
    float* __restrict__ Opart, float* __restrict__ Mpart, float* __restrict__ Lpart) {
    int blk = blockIdx.x;
    int kh = blk & (SPLIT_ - 1);
    int qt = (blk >> 2) & 7;
    int h = (blk >> 5) & 7;
    int b = blk >> 8;
    int tid = threadIdx.x, lane = tid & 63, w = tid >> 6;
    int lg = lane >> 4, lr = lane & 15;

    __shared__ __align__(16) __bf16 sK[64 * 32];
    __shared__ __align__(16) __bf16 sV[32 * 64];
    __shared__ __align__(16) __bf16 sP[4 * 16 * 72];
    __shared__ ull s_mb[64];

    const size_t bh = (size_t)b * H_ + h;
    const __bf16* Kbase = Kb + bh * NT_ * DK_;
    const __bf16* Vbase = Vt + bh * DK_ * NT_;

    int qrow = qt * 64 + w * 16 + lr;
    bf16x8 qfrag = *(const bf16x8*)(Qb + ((size_t)b * T_ + qrow) * D_ + h * DK_ + lg * 8);

    float m_run[4], l_run[4];
    f32x4 acc0 = {0.f, 0.f, 0.f, 0.f}, acc1 = {0.f, 0.f, 0.f, 0.f};
#pragma unroll
    for (int r = 0; r < 4; ++r) { m_run[r] = -1e30f; l_run[r] = 0.f; }
    const float scale = 0.1767766952966369f;

    int krow = tid >> 2, kgl = tid & 3;
    int vd = tid >> 3, vsl = tid & 7;

#pragma unroll 1
    for (int kt = 0; kt < KWORDS_ / SPLIT_; ++kt) {
        int ktg = kh * (KWORDS_ / SPLIT_) + kt;
        int k0 = ktg * 64;
        __syncthreads();
        {
            bf16x8 kc = *(const bf16x8*)(Kbase + (size_t)(k0 + krow) * DK_ + kgl * 8);
            *(bf16x8*)(sK + krow * 32 + ((kgl ^ (krow & 3)) * 8)) = kc;
            bf16x8 vc = *(const bf16x8*)(Vbase + (size_t)vd * NT_ + k0 + vsl * 8);
            *(bf16x8*)(sV + vd * 64 + ((vsl ^ (vd & 7)) * 8)) = vc;
            if (tid < 64) s_mb[tid] = bitsT[((size_t)b * KWORDS_ + ktg) * T_ + qt * 64 + tid];
        }
        __syncthreads();

        f32x4 s4[4];
#pragma unroll
        for (int sub = 0; sub < 4; ++sub) {
            int row = sub * 16 + lr;
            bf16x8 kf = *(const bf16x8*)(sK + row * 32 + ((lg ^ (row & 3)) * 8));
            f32x4 z = {0.f, 0.f, 0.f, 0.f};
            s4[sub] = __builtin_amdgcn_mfma_f32_16x16x32_bf16(qfrag, kf, z, 0, 0, 0);
        }

        ull mw[4];
#pragma unroll
        for (int r = 0; r < 4; ++r) mw[r] = s_mb[w * 16 + lg * 4 + r] >> lr;
        float sv[4][4];
#pragma unroll
        for (int sub = 0; sub < 4; ++sub)
#pragma unroll
            for (int r = 0; r < 4; ++r) {
                bool on = (mw[r] >> (sub * 16)) & 1ull;
                sv[sub][r] = on ? s4[sub][r] * scale : -1e30f;
            }
        float mx[4];
#pragma unroll
        for (int r = 0; r < 4; ++r)
            mx[r] = fmaxf(fmaxf(sv[0][r], sv[1][r]), fmaxf(sv[2][r], sv[3][r]));
#pragma unroll
        for (int o = 1; o <= 8; o <<= 1)
#pragma unroll
            for (int r = 0; r < 4; ++r) mx[r] = fmaxf(mx[r], __shfl_xor(mx[r], o, 64));
        float sc[4], mnew[4];
#pragma unroll
        for (int r = 0; r < 4; ++r) {
            float mn = fmaxf(m_run[r], mx[r]);
            sc[r] = __expf(m_run[r] - mn);
            mnew[r] = mn;
            m_run[r] = mn;
        }
        float p[4][4], psum[4] = {0.f, 0.f, 0.f, 0.f};
#pragma unroll
        for (int sub = 0; sub < 4; ++sub)
#pragma unroll
            for (int r = 0; r < 4; ++r) {
                float pv = (sv[sub][r] > -1e29f) ? __expf(sv[sub][r] - mnew[r]) : 0.f;
                p[sub][r] = pv;
                psum[r] += pv;
            }
#pragma unroll
        for (int o = 1; o <= 8; o <<= 1)
#pragma unroll
            for (int r = 0; r < 4; ++r) psum[r] += __shfl_xor(psum[r], o, 64);
#pragma unroll
        for (int r = 0; r < 4; ++r) {
            l_run[r] = l_run[r] * sc[r] + psum[r];
            acc0[r] *= sc[r];
            acc1[r] *= sc[r];
        }
#pragma unroll
        for (int sub = 0; sub < 4; ++sub)
#pragma unroll
            for (int r = 0; r < 4; ++r)
                sP[w * 1152 + (lg * 4 + r) * 72 + sub * 16 + lr] = (__bf16)p[sub][r];

#pragma unroll
        for (int kstep = 0; kstep < 2; ++kstep) {
            bf16x8 pa = *(const bf16x8*)(sP + w * 1152 + lr * 72 + kstep * 32 + lg * 8);
            {
                int d = lr;
                bf16x8 vf = *(const bf16x8*)(sV + d * 64 + (((kstep * 4 + lg) ^ (d & 7)) * 8));
                acc0 = __builtin_amdgcn_mfma_f32_16x16x32_bf16(pa, vf, acc0, 0, 0, 0);
            }
            {
                int d = 16 + lr;
                bf16x8 vf = *(const bf16x8*)(sV + d * 64 + (((kstep * 4 + lg) ^ (d & 7)) * 8));
                acc1 = __builtin_amdgcn_mfma_f32_16x16x32_bf16(pa, vf, acc1, 0, 0, 0);
            }
        }
    }

    size_t obase = (((size_t)kh * B_ + b) * H_ + h) * T_ + qt * 64;
    int qloc = w * 16 + lg * 4;
#pragma unroll
    for (int r = 0; r < 4; ++r) {
        Opart[(obase + qloc + r) * DK_ + lr] = acc0[r];
        Opart[(obase + qloc + r) * DK_ + 16 + lr] = acc1[r];
    }
    if (lr == 0) {
#pragma unroll
        for (int r = 0; r < 4; ++r) {
            Mpart[obase + qloc + r] = m_run[r];
            Lpart[obase + qloc + r] = l_run[r];
        }
    }
}

// ------------------------------------------------ merge split-K partials -> ctx f32
__global__ __launch_bounds__(256) void merge_kernel(
    const float* __restrict__ Opart, const float* __restrict__ Mpart,
    const float* __restrict__ Lpart, float* __restrict__ ctx) {
    int idx = blockIdx.x * 256 + threadIdx.x;
    int d = idx & 31;
    int t = (idx >> 5) & (T_ - 1);
    int bh = idx >> 14;
    int h = bh & 7, b = bh >> 3;
    size_t ps = (size_t)B_ * H_ * T_;
    size_t base = (size_t)bh * T_ + t;
    float m0 = Mpart[base], m1 = Mpart[ps + base], m2 = Mpart[2 * ps + base], m3 = Mpart[3 * ps + base];
    float M = fmaxf(fmaxf(m0, m1), fmaxf(m2, m3));
    float w0 = __expf(m0 - M), w1 = __expf(m1 - M), w2 = __expf(m2 - M), w3 = __expf(m3 - M);
    float L = w0 * Lpart[base] + w1 * Lpart[ps + base] + w2 * Lpart[2 * ps + base] + w3 * Lpart[3 * ps + base];
    float o = w0 * Opart[base * DK_ + d] + w1 * Opart[(ps + base) * DK_ + d] +
              w2 * Opart[(2 * ps + base) * DK_ + d] + w3 * Opart[(3 * ps + base) * DK_ + d];
    ctx[((size_t)b * T_ + t) * D_ + h * DK_ + d] = o / L;
}

// ------------------------------------------------ out = xq + ctx@Wo + bo
__global__ __launch_bounds__(256) void out_kernel(
    const float* __restrict__ ctx, const float* __restrict__ xq,
    const float* __restrict__ Wo, const float* __restrict__ bo, float* __restrict__ out) {
    int blk = blockIdx.x;
    int t0 = (blk & 31) * 16;
    int b = blk >> 5;
    int tid = threadIdx.x;
    __shared__ float s_c[16][D_];
    for (int r = 0; r < 16; ++r)
        s_c[r][tid] = ctx[((size_t)b * T_ + t0 + r) * D_ + tid];
    __syncthreads();
    float acc[16];
#pragma unroll
    for (int r = 0; r < 16; ++r) acc[r] = bo[tid];
    for (int e = 0; e < D_; ++e) {
        float w = Wo[e * D_ + tid];
#pragma unroll
        for (int r = 0; r < 16; ++r) acc[r] += s_c[r][e] * w;
    }
    for (int r = 0; r < 16; ++r) {
        size_t off = ((size_t)b * T_ + t0 + r) * D_ + tid;
        out[off] = xq[off] + acc[r];
    }
}

// ---------------------------------------------------------------- launcher
extern "C" void kernel_launch(void* const* d_in, const int* in_sizes, int n_in,
                              void* d_out, int out_size, void* d_ws, size_t ws_size,
                              hipStream_t stream) {
    const float* x = (const float*)d_in[0];
    const float* md = (const float*)d_in[1];
    const float* na = (const float*)d_in[2];
    const float* ea = (const float*)d_in[3];
    const int* mask = (const int*)d_in[4];
    const float* W_ts1 = (const float*)d_in[5];
    const float* b_ts1 = (const float*)d_in[6];
    const float* W_ts2 = (const float*)d_in[7];
    const float* b_ts2 = (const float*)d_in[8];
    const float* W_a1 = (const float*)d_in[9];
    const float* b_a1 = (const float*)d_in[10];
    const float* W_a2 = (const float*)d_in[11];
    const float* b_a2 = (const float*)d_in[12];
    const float* W_e1 = (const float*)d_in[13];
    const float* b_e1 = (const float*)d_in[14];
    const float* W_e2 = (const float*)d_in[15];
    const float* b_e2 = (const float*)d_in[16];
    const float* Wq = (const float*)d_in[17];
    const float* bq = (const float*)d_in[18];
    const float* Wk = (const float*)d_in[19];
    const float* bk = (const float*)d_in[20];
    const float* Wv = (const float*)d_in[21];
    const float* bv = (const float*)d_in[22];
    const float* Wo = (const float*)d_in[23];
    const float* bo = (const float*)d_in[24];
    const float* ln_g = (const float*)d_in[25];
    const float* ln_b = (const float*)d_in[26];
    float* out = (float*)d_out;

    char* ws = (char*)d_ws;
    float* pe = (float*)ws;    ws += (size_t)T_ * D_ * 4;
    ull* bitsT = (ull*)ws;     ws += (size_t)B_ * KWORDS_ * T_ * 8;
    __bf16* Kb = (__bf16*)ws;  ws += (size_t)B_ * H_ * NT_ * DK_ * 2;
    __bf16* Vt = (__bf16*)ws;  ws += (size_t)B_ * H_ * DK_ * NT_ * 2;
    float* xq = (float*)ws;    ws += (size_t)B_ * T_ * D_ * 4;
    __bf16* Qb = (__bf16*)ws;  ws += (size_t)B_ * T_ * D_ * 2;
    float* ctx = (float*)ws;   ws += (size_t)B_ * T_ * D_ * 4;
    float* Opart = (float*)ws; ws += (size_t)SPLIT_ * B_ * H_ * T_ * DK_ * 4;
    float* Mpart = (float*)ws; ws += (size_t)SPLIT_ * B_ * H_ * T_ * 4;
    float* Lpart = (float*)ws; ws += (size_t)SPLIT_ * B_ * H_ * T_ * 4;
    // bf16 prepped weights
    __bf16* ts1P = (__bf16*)ws; ws += 6144 * 2;
    __bf16* a1P = (__bf16*)ws;  ws += 2048 * 2;
    __bf16* e1P = (__bf16*)ws;  ws += 8192 * 2;
    __bf16* ts2T = (__bf16*)ws; ws += 36864 * 2;
    __bf16* a2T = (__bf16*)ws;  ws += 4096 * 2;
    __bf16* e2T = (__bf16*)ws;  ws += 65536 * 2;
    __bf16* WkT = (__bf16*)ws;  ws += 65536 * 2;
    __bf16* WvT = (__bf16*)ws;  ws += 65536 * 2;

    pe_kernel<<<T_, 256, 0, stream>>>(pe);
    maskbits_kernel<<<B_ * T_, 256, 0, stream>>>(mask, bitsT);
    wprep_kernel<<<992, 256, 0, stream>>>(W_ts1, W_a1, W_e1, W_ts2, W_a2, W_e2, Wk, Wv,
                                          ts1P, a1P, e1P, ts2T, a2T, e2T, WkT, WvT);
    kv_mfma_kernel<<<B_ * N_ * (T_ / 64), 256, 0, stream>>>(
        md, na, ea, ts1P, a1P, e1P, b_ts1, b_a1, b_e1,
        ts2T, a2T, e2T, b_ts2, b_a2, b_e2, WkT, bk, WvT, bv, pe, Kb, Vt);
    q_kernel<<<B_ * (T_ / 16), 256, 0, stream>>>(x, pe, Wq, bq, ln_g, ln_b, xq, Qb);
    attn_mfma_kernel<<<B_ * H_ * (T_ / 64) * SPLIT_, 256, 0, stream>>>(
        Qb, Kb, Vt, bitsT, Opart, Mpart, Lpart);
    merge_kernel<<<(B_ * H_ * T_ * DK_) / 256, 256, 0, stream>>>(Opart, Mpart, Lpart, ctx);
    out_kernel<<<B_ * (T_ / 16), 256, 0, stream>>>(ctx, xq, Wo, bo, out);
}

// Round 4
// 280.033 us; speedup vs baseline: 5.6319x; 1.0844x over previous
//
#include <hip/hip_runtime.h>
#include <hip/hip_bf16.h>

#define B_ 4
#define T_ 512
#define N_ 16
#define D_ 256
#define H_ 8
#define DK_ 32
#define NT_ (N_ * T_)
#define CTS_ 6
#define CN_ 4
#define CE_ 3
#define TSE_ 192
#define AUXE_ 64
#define SPLIT_ 4
#define KWORDS_ (NT_ / 64)   // 128 mask words per row

typedef unsigned long long ull;
typedef __bf16 bf16x8 __attribute__((ext_vector_type(8)));
typedef float f32x4 __attribute__((ext_vector_type(4)));

// ---------------------------------------------------------------- PE table
__global__ __launch_bounds__(256) void pe_kernel(float* pe) {
    int t = blockIdx.x;
    int d = threadIdx.x;
    int j = d >> 1;
    float div = expf((float)(2 * j) * (-9.210340371976184f / 256.0f)); // -ln(10000)/D
    float a = (float)t * div;
    pe[t * D_ + d] = (d & 1) ? cosf(a) : sinf(a);
}

// ------------------------------------- mask -> transposed bitmask [B][128][T]
__global__ __launch_bounds__(256) void maskbits_kernel(const int* __restrict__ mask,
                                                       ull* __restrict__ bitsT) {
    int row = blockIdx.x;  // b*T + t
    int b = row >> 9, t = row & (T_ - 1);
    const int* mrow = mask + (size_t)row * NT_;
    int lane = threadIdx.x & 63, wave = threadIdx.x >> 6;
    for (int it = 0; it < NT_ / 256; ++it) {
        int k = it * 256 + wave * 64 + lane;
        ull bal = __ballot(mrow[k] != 0);
        if (lane == 0) bitsT[((size_t)b * KWORDS_ + (k >> 6)) * T_ + t] = bal;
    }
}

// -------------------------------- weight prep: bf16, fragment-tiled layouts
// First layers (K=32): [col][k] is already fragment-contiguous per 16-col tile.
// Second layers / projections: 16col x 32k tiles, tile-major:
//   out[((ct*KS+ks)*16 + lr)*32 + kk] = W[(ks*32+kk)*COLS + ct*16+lr]
// sizes: ts1P 6144, a1P 2048, e1P 8192, ts2T 36864 (KS=6), a2T 4096 (KS=2),
//        e2T 65536 (KS=8), WkT 65536, WvT 65536 -> total 253952, grid 992*256
__global__ __launch_bounds__(256) void wprep_kernel(
    const float* __restrict__ W_ts1, const float* __restrict__ W_a1,
    const float* __restrict__ W_e1, const float* __restrict__ W_ts2,
    const float* __restrict__ W_a2, const float* __restrict__ W_e2,
    const float* __restrict__ Wk, const float* __restrict__ Wv,
    __bf16* __restrict__ ts1P, __bf16* __restrict__ a1P, __bf16* __restrict__ e1P,
    __bf16* __restrict__ ts2T, __bf16* __restrict__ a2T, __bf16* __restrict__ e2T,
    __bf16* __restrict__ WkT, __bf16* __restrict__ WvT) {
    int i = blockIdx.x * 256 + threadIdx.x;
    if (i < 6144) { int col = i >> 5, k = i & 31;
        ts1P[i] = (__bf16)(k < 6 ? W_ts1[k * TSE_ + col] : 0.f); return; }
    i -= 6144;
    if (i < 2048) { int col = i >> 5, k = i & 31;
        a1P[i] = (__bf16)((k >= 6 && k < 10) ? W_a1[(k - 6) * AUXE_ + col] : 0.f); return; }
    i -= 2048;
    if (i < 8192) { int col = i >> 5, k = i & 31;
        e1P[i] = (__bf16)((k >= 10 && k < 13) ? W_e1[(k - 10) * D_ + col] : 0.f); return; }
    i -= 8192;
    if (i < 36864) {  // ts2: COLS=192, KS=6
        int tile = i >> 9, lr = (i >> 5) & 15, kk = i & 31;
        int ct = tile / 6, ks = tile % 6;
        ts2T[i] = (__bf16)W_ts2[(ks * 32 + kk) * TSE_ + ct * 16 + lr]; return; }
    i -= 36864;
    if (i < 4096) {   // a2: COLS=64, KS=2
        int tile = i >> 9, lr = (i >> 5) & 15, kk = i & 31;
        int ct = tile / 2, ks = tile % 2;
        a2T[i] = (__bf16)W_a2[(ks * 32 + kk) * AUXE_ + ct * 16 + lr]; return; }
    i -= 4096;
    if (i < 65536) {  // e2: COLS=256, KS=8
        int tile = i >> 9, lr = (i >> 5) & 15, kk = i & 31;
        int ct = tile >> 3, ks = tile & 7;
        e2T[i] = (__bf16)W_e2[(ks * 32 + kk) * D_ + ct * 16 + lr]; return; }
    i -= 65536;
    if (i < 65536) {  // Wk
        int tile = i >> 9, lr = (i >> 5) & 15, kk = i & 31;
        int ct = tile >> 3, ks = tile & 7;
        WkT[i] = (__bf16)Wk[(ks * 32 + kk) * D_ + ct * 16 + lr]; return; }
    i -= 65536;
    {                 // Wv
        int tile = i >> 9, lr = (i >> 5) & 15, kk = i & 31;
        int ct = tile >> 3, ks = tile & 7;
        WvT[i] = (__bf16)Wv[(ks * 32 + kk) * D_ + ct * 16 + lr]; }
}

// ------------------------- MFMA kv chain: 64 rows/block, 4 waves x 16-row tiles
__global__ __launch_bounds__(256, 2) void kv_mfma_kernel(
    const float* __restrict__ md, const float* __restrict__ na, const float* __restrict__ ea,
    const __bf16* __restrict__ ts1P, const __bf16* __restrict__ a1P,
    const __bf16* __restrict__ e1P,
    const float* __restrict__ b_ts1, const float* __restrict__ b_a1,
    const float* __restrict__ b_e1,
    const __bf16* __restrict__ ts2T, const __bf16* __restrict__ a2T,
    const __bf16* __restrict__ e2T,
    const float* __restrict__ b_ts2, const float* __restrict__ b_a2,
    const float* __restrict__ b_e2,
    const __bf16* __restrict__ WkT, const float* __restrict__ bk,
    const __bf16* __restrict__ WvT, const float* __restrict__ bv,
    const float* __restrict__ pe, __bf16* __restrict__ Kb, __bf16* __restrict__ Vt) {
    int blk = blockIdx.x;          // 4b * 16n * 8t = 512
    int t0 = (blk & 7) * 64;
    int n = (blk >> 3) & 15;
    int b = blk >> 7;
    int tid = threadIdx.x, lane = tid & 63, w = tid >> 6;
    int lr = lane & 15, lg = lane >> 4;

    __shared__ __bf16 sA[64 * 40];      // A_all: 13 channels + zero pad to K=32
    __shared__ __bf16 sU[34304];        // union: {hts,haux,hedge} then {skey,sval}
    __bf16* hts = sU;                   // [64][200]
    __bf16* haux = sU + 12800;          // [64][72]
    __bf16* hedge = sU + 17408;         // [64][264]
    __bf16* skey = sU;                  // [64][264]
    __bf16* sval = sU + 16896;          // [64][264]

    for (int i = tid; i < 64 * 40; i += 256) sA[i] = (__bf16)0.f;
    __syncthreads();
    {
        int t = tid & 63, cg = tid >> 6;
        size_t bn = (size_t)b * N_ + n;
        for (int c = cg; c < 13; c += 4) {
            float v;
            if (c < 6) v = md[(bn * CTS_ + c) * T_ + t0 + t];
            else if (c < 10) v = na[(bn * CN_ + (c - 6)) * T_ + t0 + t];
            else v = ea[(bn * CE_ + (c - 10)) * T_ + t0 + t];
            sA[t * 40 + c] = (__bf16)v;
        }
    }
    __syncthreads();

    int arow = w * 16 + lr;       // A-fragment row
    int crow = w * 16 + lg * 4;   // C-fragment row base (+reg)
    bf16x8 afrag1 = *(const bf16x8*)(sA + arow * 40 + lg * 8);
    int foff = lr * 32 + lg * 8;  // per-lane offset within a 512-elem fragment tile

    // ---- phase 2: first layers (K=32, one MFMA per col-tile), ReLU, store bf16
#pragma unroll 1
    for (int ct = 0; ct < 12; ++ct) {
        int gcol = ct * 16 + lr;
        bf16x8 bf = *(const bf16x8*)(ts1P + ct * 512 + foff);
        f32x4 z = {0.f, 0.f, 0.f, 0.f};
        f32x4 c = __builtin_amdgcn_mfma_f32_16x16x32_bf16(afrag1, bf, z, 0, 0, 0);
        float bias = b_ts1[gcol];
#pragma unroll
        for (int r = 0; r < 4; ++r) hts[(crow + r) * 200 + gcol] = (__bf16)fmaxf(c[r] + bias, 0.f);
    }
#pragma unroll 1
    for (int ct = 0; ct < 4; ++ct) {
        int gcol = ct * 16 + lr;
        bf16x8 bf = *(const bf16x8*)(a1P + ct * 512 + foff);
        f32x4 z = {0.f, 0.f, 0.f, 0.f};
        f32x4 c = __builtin_amdgcn_mfma_f32_16x16x32_bf16(afrag1, bf, z, 0, 0, 0);
        float bias = b_a1[gcol];
#pragma unroll
        for (int r = 0; r < 4; ++r) haux[(crow + r) * 72 + gcol] = (__bf16)fmaxf(c[r] + bias, 0.f);
    }
#pragma unroll 1
    for (int ct = 0; ct < 16; ++ct) {
        int gcol = ct * 16 + lr;
        bf16x8 bf = *(const bf16x8*)(e1P + ct * 512 + foff);
        f32x4 z = {0.f, 0.f, 0.f, 0.f};
        f32x4 c = __builtin_amdgcn_mfma_f32_16x16x32_bf16(afrag1, bf, z, 0, 0, 0);
        float bias = b_e1[gcol];
#pragma unroll
        for (int r = 0; r < 4; ++r) hedge[(crow + r) * 264 + gcol] = (__bf16)fmaxf(c[r] + bias, 0.f);
    }
    __syncthreads();

    // ---- phase 3: nbr (ts2|a2) and edg (e2) accumulators in registers
    f32x4 nacc[16], eacc[16];
#pragma unroll
    for (int ct = 0; ct < 16; ++ct) {
        nacc[ct] = (f32x4){0.f, 0.f, 0.f, 0.f};
        eacc[ct] = (f32x4){0.f, 0.f, 0.f, 0.f};
    }
#pragma unroll 1
    for (int ks = 0; ks < 8; ++ks) {
        bf16x8 af = *(const bf16x8*)(hedge + arow * 264 + ks * 32 + lg * 8);
#pragma unroll
        for (int ct = 0; ct < 16; ++ct) {
            bf16x8 bf = *(const bf16x8*)(e2T + (ct * 8 + ks) * 512 + foff);
            eacc[ct] = __builtin_amdgcn_mfma_f32_16x16x32_bf16(af, bf, eacc[ct], 0, 0, 0);
        }
    }
#pragma unroll 1
    for (int ks = 0; ks < 6; ++ks) {
        bf16x8 af = *(const bf16x8*)(hts + arow * 200 + ks * 32 + lg * 8);
#pragma unroll
        for (int ct = 0; ct < 12; ++ct) {
            bf16x8 bf = *(const bf16x8*)(ts2T + (ct * 6 + ks) * 512 + foff);
            nacc[ct] = __builtin_amdgcn_mfma_f32_16x16x32_bf16(af, bf, nacc[ct], 0, 0, 0);
        }
    }
#pragma unroll
    for (int ks = 0; ks < 2; ++ks) {
        bf16x8 af = *(const bf16x8*)(haux + arow * 72 + ks * 32 + lg * 8);
#pragma unroll
        for (int ct = 0; ct < 4; ++ct) {
            bf16x8 bf = *(const bf16x8*)(a2T + (ct * 2 + ks) * 512 + foff);
            nacc[12 + ct] = __builtin_amdgcn_mfma_f32_16x16x32_bf16(af, bf, nacc[12 + ct], 0, 0, 0);
        }
    }
    __syncthreads();   // hts/haux/hedge reads done; safe to overwrite union

    // ---- phase 3b: key = nbr*edg + pe, val = nbr + pe (bf16 into LDS)
#pragma unroll
    for (int ct = 0; ct < 16; ++ct) {
        int gcol = ct * 16 + lr;
        float nb_bias = (ct < 12) ? b_ts2[gcol] : b_a2[gcol - 192];
        float ed_bias = b_e2[gcol];
#pragma unroll
        for (int r = 0; r < 4; ++r) {
            int row = crow + r;
            float p = pe[(t0 + row) * D_ + gcol];
            float nb = nacc[ct][r] + nb_bias;
            float ed = eacc[ct][r] + ed_bias;
            skey[row * 264 + gcol] = (__bf16)(nb * ed + p);
            sval[row * 264 + gcol] = (__bf16)(nb + p);
        }
    }
    __syncthreads();

    // ---- phase 4: K/V projections (K=256 -> 8 ksteps per col-tile)
    size_t key0 = (size_t)n * T_ + t0;
#pragma unroll 1
    for (int ct = 0; ct < 16; ++ct) {
        int gcol = ct * 16 + lr;
        f32x4 ka = {0.f, 0.f, 0.f, 0.f}, va = {0.f, 0.f, 0.f, 0.f};
#pragma unroll
        for (int ks = 0; ks < 8; ++ks) {
            bf16x8 afk = *(const bf16x8*)(skey + arow * 264 + ks * 32 + lg * 8);
            bf16x8 afv = *(const bf16x8*)(sval + arow * 264 + ks * 32 + lg * 8);
            bf16x8 b8k = *(const bf16x8*)(WkT + (ct * 8 + ks) * 512 + foff);
            bf16x8 b8v = *(const bf16x8*)(WvT + (ct * 8 + ks) * 512 + foff);
            ka = __builtin_amdgcn_mfma_f32_16x16x32_bf16(afk, b8k, ka, 0, 0, 0);
            va = __builtin_amdgcn_mfma_f32_16x16x32_bf16(afv, b8v, va, 0, 0, 0);
        }
        float kbias = bk[gcol], vbias = bv[gcol];
        int h = gcol >> 5, dd = gcol & 31;
        size_t bh = (size_t)b * H_ + h;
#pragma unroll
        for (int r = 0; r < 4; ++r)
            Kb[(bh * NT_ + key0 + crow + r) * DK_ + dd] = (__bf16)(ka[r] + kbias);
        __bf16 tmp[4];
#pragma unroll
        for (int r = 0; r < 4; ++r) tmp[r] = (__bf16)(va[r] + vbias);
        *(ushort4*)(Vt + (bh * DK_ + dd) * NT_ + key0 + crow) = *(ushort4*)tmp;
    }
}

// -------------------------- xq = x + pe, LayerNorm, Q proj -> bf16 Qb [b][t][256]
__global__ __launch_bounds__(256) void q_kernel(
    const float* __restrict__ x, const float* __restrict__ pe,
    const float* __restrict__ Wq, const float* __restrict__ bq,
    const float* __restrict__ ln_g, const float* __restrict__ ln_b,
    float* __restrict__ xq, __bf16* __restrict__ Qb) {
    int blk = blockIdx.x;
    int t0 = (blk & 31) * 16;
    int b = blk >> 5;
    int tid = threadIdx.x;

    __shared__ float s_xn[16][D_];
    __shared__ float s_red[8];

    for (int r = 0; r < 16; ++r) {
        int t = t0 + r;
        size_t off = ((size_t)b * T_ + t) * D_ + tid;
        float v = x[off] + pe[t * D_ + tid];
        xq[off] = v;
        float s1 = v, s2 = v * v;
#pragma unroll
        for (int o = 32; o; o >>= 1) {
            s1 += __shfl_down(s1, o, 64);
            s2 += __shfl_down(s2, o, 64);
        }
        if ((tid & 63) == 0) {
            s_red[tid >> 6] = s1;
            s_red[4 + (tid >> 6)] = s2;
        }
        __syncthreads();
        float t1 = s_red[0] + s_red[1] + s_red[2] + s_red[3];
        float t2 = s_red[4] + s_red[5] + s_red[6] + s_red[7];
        float mu = t1 * (1.f / D_);
        float var = t2 * (1.f / D_) - mu * mu;
        float rs = rsqrtf(var + 1e-6f);
        s_xn[r][tid] = (v - mu) * rs * ln_g[tid] + ln_b[tid];
        __syncthreads();
    }

    float acc[16];
#pragma unroll
    for (int r = 0; r < 16; ++r) acc[r] = bq[tid];
    for (int e = 0; e < D_; ++e) {
        float w = Wq[e * D_ + tid];
#pragma unroll
        for (int r = 0; r < 16; ++r) acc[r] += s_xn[r][e] * w;
    }
    for (int r = 0; r < 16; ++r) {
        Qb[((size_t)b * T_ + t0 + r) * D_ + tid] = (__bf16)acc[r];
    }
}

// ----------------------------------- MFMA flash attention, split-K partials
__global__ __launch_bounds__(256) void attn_mfma_kernel(
    const __bf16* __restrict__ Qb, const __bf16* __restrict__ Kb,
    const __bf16* __restrict__ Vt, const ull* __restrict__ bitsT,
    float* __restrict__ Opart, float* __restrict__ Mpart, float* __restrict__ Lpart) {
    int blk = blockIdx.x;
    int kh = blk & (SPLIT_ - 1);
    int qt = (blk >> 2) & 7;
    int h = (blk >> 5) & 7;
    int b = blk >> 8;
    int tid = threadIdx.x, lane = tid & 63, w = tid >> 6;
    int lg = lane >> 4, lr = lane & 15;

    __shared__ __align__(16) __bf16 sK[64 * 32];
    __shared__ __align__(16) __bf16 sV[32 * 64];
    __shared__ __align__(16) __bf16 sP[4 * 16 * 72];
    __shared__ ull s_mb[64];

    const size_t bh = (size_t)b * H_ + h;
    const __bf16* Kbase = Kb + bh * NT_ * DK_;
    const __bf16* Vbase = Vt + bh * DK_ * NT_;

    int qrow = qt * 64 + w * 16 + lr;
    bf16x8 qfrag = *(const bf16x8*)(Qb + ((size_t)b * T_ + qrow) * D_ + h * DK_ + lg * 8);

    float m_run[4], l_run[4];
    f32x4 acc0 = {0.f, 0.f, 0.f, 0.f}, acc1 = {0.f, 0.f, 0.f, 0.f};
#pragma unroll
    for (int r = 0; r < 4; ++r) { m_run[r] = -1e30f; l_run[r] = 0.f; }
    const float scale = 0.1767766952966369f;

    int krow = tid >> 2, kgl = tid & 3;
    int vd = tid >> 3, vsl = tid & 7;

#pragma unroll 1
    for (int kt = 0; kt < KWORDS_ / SPLIT_; ++kt) {
        int ktg = kh * (KWORDS_ / SPLIT_) + kt;
        int k0 = ktg * 64;
        __syncthreads();
        {
            bf16x8 kc = *(const bf16x8*)(Kbase + (size_t)(k0 + krow) * DK_ + kgl * 8);
            *(bf16x8*)(sK + krow * 32 + ((kgl ^ (krow & 3)) * 8)) = kc;
            bf16x8 vc = *(const bf16x8*)(Vbase + (size_t)vd * NT_ + k0 + vsl * 8);
            *(bf16x8*)(sV + vd * 64 + ((vsl ^ (vd & 7)) * 8)) = vc;
            if (tid < 64) s_mb[tid] = bitsT[((size_t)b * KWORDS_ + ktg) * T_ + qt * 64 + tid];
        }
        __syncthreads();

        f32x4 s4[4];
#pragma unroll
        for (int sub = 0; sub < 4; ++sub) {
            int row = sub * 16 + lr;
            bf16x8 kf = *(const bf16x8*)(sK + row * 32 + ((lg ^ (row & 3)) * 8));
            f32x4 z = {0.f, 0.f, 0.f, 0.f};
            s4[sub] = __builtin_amdgcn_mfma_f32_16x16x32_bf16(qfrag, kf, z, 0, 0, 0);
        }

        ull mw[4];
#pragma unroll
        for (int r = 0; r < 4; ++r) mw[r] = s_mb[w * 16 + lg * 4 + r] >> lr;
        float sv[4][4];
#pragma unroll
        for (int sub = 0; sub < 4; ++sub)
#pragma unroll
            for (int r = 0; r < 4; ++r) {
                bool on = (mw[r] >> (sub * 16)) & 1ull;
                sv[sub][r] = on ? s4[sub][r] * scale : -1e30f;
            }
        float mx[4];
#pragma unroll
        for (int r = 0; r < 4; ++r)
            mx[r] = fmaxf(fmaxf(sv[0][r], sv[1][r]), fmaxf(sv[2][r], sv[3][r]));
#pragma unroll
        for (int o = 1; o <= 8; o <<= 1)
#pragma unroll
            for (int r = 0; r < 4; ++r) mx[r] = fmaxf(mx[r], __shfl_xor(mx[r], o, 64));
        float sc[4], mnew[4];
#pragma unroll
        for (int r = 0; r < 4; ++r) {
            float mn = fmaxf(m_run[r], mx[r]);
            sc[r] = __expf(m_run[r] - mn);
            mnew[r] = mn;
            m_run[r] = mn;
        }
        float p[4][4], psum[4] = {0.f, 0.f, 0.f, 0.f};
#pragma unroll
        for (int sub = 0; sub < 4; ++sub)
#pragma unroll
            for (int r = 0; r < 4; ++r) {
                float pv = (sv[sub][r] > -1e29f) ? __expf(sv[sub][r] - mnew[r]) : 0.f;
                p[sub][r] = pv;
                psum[r] += pv;
            }
#pragma unroll
        for (int o = 1; o <= 8; o <<= 1)
#pragma unroll
            for (int r = 0; r < 4; ++r) psum[r] += __shfl_xor(psum[r], o, 64);
#pragma unroll
        for (int r = 0; r < 4; ++r) {
            l_run[r] = l_run[r] * sc[r] + psum[r];
            acc0[r] *= sc[r];
            acc1[r] *= sc[r];
        }
#pragma unroll
        for (int sub = 0; sub < 4; ++sub)
#pragma unroll
            for (int r = 0; r < 4; ++r)
                sP[w * 1152 + (lg * 4 + r) * 72 + sub * 16 + lr] = (__bf16)p[sub][r];

#pragma unroll
        for (int kstep = 0; kstep < 2; ++kstep) {
            bf16x8 pa = *(const bf16x8*)(sP + w * 1152 + lr * 72 + kstep * 32 + lg * 8);
            {
                int d = lr;
                bf16x8 vf = *(const bf16x8*)(sV + d * 64 + (((kstep * 4 + lg) ^ (d & 7)) * 8));
                acc0 = __builtin_amdgcn_mfma_f32_16x16x32_bf16(pa, vf, acc0, 0, 0, 0);
            }
            {
                int d = 16 + lr;
                bf16x8 vf = *(const bf16x8*)(sV + d * 64 + (((kstep * 4 + lg) ^ (d & 7)) * 8));
                acc1 = __builtin_amdgcn_mfma_f32_16x16x32_bf16(pa, vf, acc1, 0, 0, 0);
            }
        }
    }

    size_t obase = (((size_t)kh * B_ + b) * H_ + h) * T_ + qt * 64;
    int qloc = w * 16 + lg * 4;
#pragma unroll
    for (int r = 0; r < 4; ++r) {
        Opart[(obase + qloc + r) * DK_ + lr] = acc0[r];
        Opart[(obase + qloc + r) * DK_ + 16 + lr] = acc1[r];
    }
    if (lr == 0) {
#pragma unroll
        for (int r = 0; r < 4; ++r) {
            Mpart[obase + qloc + r] = m_run[r];
            Lpart[obase + qloc + r] = l_run[r];
        }
    }
}

// ------------------------------------------------ merge split-K partials -> ctx f32
__global__ __launch_bounds__(256) void merge_kernel(
    const float* __restrict__ Opart, const float* __restrict__ Mpart,
    const float* __restrict__ Lpart, float* __restrict__ ctx) {
    int idx = blockIdx.x * 256 + threadIdx.x;
    int d = idx & 31;
    int t = (idx >> 5) & (T_ - 1);
    int bh = idx >> 14;
    int h = bh & 7, b = bh >> 3;
    size_t ps = (size_t)B_ * H_ * T_;
    size_t base = (size_t)bh * T_ + t;
    float m0 = Mpart[base], m1 = Mpart[ps + base], m2 = Mpart[2 * ps + base], m3 = Mpart[3 * ps + base];
    float M = fmaxf(fmaxf(m0, m1), fmaxf(m2, m3));
    float w0 = __expf(m0 - M), w1 = __expf(m1 - M), w2 = __expf(m2 - M), w3 = __expf(m3 - M);
    float L = w0 * Lpart[base] + w1 * Lpart[ps + base] + w2 * Lpart[2 * ps + base] + w3 * Lpart[3 * ps + base];
    float o = w0 * Opart[base * DK_ + d] + w1 * Opart[(ps + base) * DK_ + d] +
              w2 * Opart[(2 * ps + base) * DK_ + d] + w3 * Opart[(3 * ps + base) * DK_ + d];
    ctx[((size_t)b * T_ + t) * D_ + h * DK_ + d] = o / L;
}

// ------------------------------------------------ out = xq + ctx@Wo + bo
__global__ __launch_bounds__(256) void out_kernel(
    const float* __restrict__ ctx, const float* __restrict__ xq,
    const float* __restrict__ Wo, const float* __restrict__ bo, float* __restrict__ out) {
    int blk = blockIdx.x;
    int t0 = (blk & 31) * 16;
    int b = blk >> 5;
    int tid = threadIdx.x;
    __shared__ float s_c[16][D_];
    for (int r = 0; r < 16; ++r)
        s_c[r][tid] = ctx[((size_t)b * T_ + t0 + r) * D_ + tid];
    __syncthreads();
    float acc[16];
#pragma unroll
    for (int r = 0; r < 16; ++r) acc[r] = bo[tid];
    for (int e = 0; e < D_; ++e) {
        float w = Wo[e * D_ + tid];
#pragma unroll
        for (int r = 0; r < 16; ++r) acc[r] += s_c[r][e] * w;
    }
    for (int r = 0; r < 16; ++r) {
        size_t off = ((size_t)b * T_ + t0 + r) * D_ + tid;
        out[off] = xq[off] + acc[r];
    }
}

// ---------------------------------------------------------------- launcher
extern "C" void kernel_launch(void* const* d_in, const int* in_sizes, int n_in,
                              void* d_out, int out_size, void* d_ws, size_t ws_size,
                              hipStream_t stream) {
    const float* x = (const float*)d_in[0];
    const float* md = (const float*)d_in[1];
    const float* na = (const float*)d_in[2];
    const float* ea = (const float*)d_in[3];
    const int* mask = (const int*)d_in[4];
    const float* W_ts1 = (const float*)d_in[5];
    const float* b_ts1 = (const float*)d_in[6];
    const float* W_ts2 = (const float*)d_in[7];
    const float* b_ts2 = (const float*)d_in[8];
    const float* W_a1 = (const float*)d_in[9];
    const float* b_a1 = (const float*)d_in[10];
    const float* W_a2 = (const float*)d_in[11];
    const float* b_a2 = (const float*)d_in[12];
    const float* W_e1 = (const float*)d_in[13];
    const float* b_e1 = (const float*)d_in[14];
    const float* W_e2 = (const float*)d_in[15];
    const float* b_e2 = (const float*)d_in[16];
    const float* Wq = (const float*)d_in[17];
    const float* bq = (const float*)d_in[18];
    const float* Wk = (const float*)d_in[19];
    const float* bk = (const float*)d_in[20];
    const float* Wv = (const float*)d_in[21];
    const float* bv = (const float*)d_in[22];
    const float* Wo = (const float*)d_in[23];
    const float* bo = (const float*)d_in[24];
    const float* ln_g = (const float*)d_in[25];
    const float* ln_b = (const float*)d_in[26];
    float* out = (float*)d_out;

    char* ws = (char*)d_ws;
    float* pe = (float*)ws;    ws += (size_t)T_ * D_ * 4;
    ull* bitsT = (ull*)ws;     ws += (size_t)B_ * KWORDS_ * T_ * 8;
    __bf16* Kb = (__bf16*)ws;  ws += (size_t)B_ * H_ * NT_ * DK_ * 2;
    __bf16* Vt = (__bf16*)ws;  ws += (size_t)B_ * H_ * DK_ * NT_ * 2;
    float* xq = (float*)ws;    ws += (size_t)B_ * T_ * D_ * 4;
    __bf16* Qb = (__bf16*)ws;  ws += (size_t)B_ * T_ * D_ * 2;
    float* ctx = (float*)ws;   ws += (size_t)B_ * T_ * D_ * 4;
    float* Opart = (float*)ws; ws += (size_t)SPLIT_ * B_ * H_ * T_ * DK_ * 4;
    float* Mpart = (float*)ws; ws += (size_t)SPLIT_ * B_ * H_ * T_ * 4;
    float* Lpart = (float*)ws; ws += (size_t)SPLIT_ * B_ * H_ * T_ * 4;
    // bf16 prepped weights
    __bf16* ts1P = (__bf16*)ws; ws += 6144 * 2;
    __bf16* a1P = (__bf16*)ws;  ws += 2048 * 2;
    __bf16* e1P = (__bf16*)ws;  ws += 8192 * 2;
    __bf16* ts2T = (__bf16*)ws; ws += 36864 * 2;
    __bf16* a2T = (__bf16*)ws;  ws += 4096 * 2;
    __bf16* e2T = (__bf16*)ws;  ws += 65536 * 2;
    __bf16* WkT = (__bf16*)ws;  ws += 65536 * 2;
    __bf16* WvT = (__bf16*)ws;  ws += 65536 * 2;

    pe_kernel<<<T_, 256, 0, stream>>>(pe);
    maskbits_kernel<<<B_ * T_, 256, 0, stream>>>(mask, bitsT);
    wprep_kernel<<<992, 256, 0, stream>>>(W_ts1, W_a1, W_e1, W_ts2, W_a2, W_e2, Wk, Wv,
                                          ts1P, a1P, e1P, ts2T, a2T, e2T, WkT, WvT);
    kv_mfma_kernel<<<B_ * N_ * (T_ / 64), 256, 0, stream>>>(
        md, na, ea, ts1P, a1P, e1P, b_ts1, b_a1, b_e1,
        ts2T, a2T, e2T, b_ts2, b_a2, b_e2, WkT, bk, WvT, bv, pe, Kb, Vt);
    q_kernel<<<B_ * (T_ / 16), 256, 0, stream>>>(x, pe, Wq, bq, ln_g, ln_b, xq, Qb);
    attn_mfma_kernel<<<B_ * H_ * (T_ / 64) * SPLIT_, 256, 0, stream>>>(
        Qb, Kb, Vt, bitsT, Opart, Mpart, Lpart);
    merge_kernel<<<(B_ * H_ * T_ * DK_) / 256, 256, 0, stream>>>(Opart, Mpart, Lpart, ctx);
    out_kernel<<<B_ * (T_ / 16), 256, 0, stream>>>(ctx, xq, Wo, bo, out);
}